// Round 15
// baseline (253.785 us; speedup 1.0000x reference)
//
#include <hip/hip_runtime.h>
#include <hip/hip_cooperative_groups.h>
#include <cstdint>
#include <cstddef>

namespace cg = cooperative_groups;

#define N_NODES 50000
#define N_EDGES 800000
#define CAP 64        // max in-degree; Poisson(16): P(>64) astronomically small

#define BIN_SZ 512                    // nodes per bin (pow2: bin = dst>>9)
#define NBIN 98                       // ceil(50000/512)
#define NSLOT 64                      // per-(bin,part) slot; Binom(2048,.0102) mean 21, +9.5 sigma

#define CHUNK_A 2048
#define N_PARTS 391                   // 391*2048 = 800768 >= 800000

// phase A tasks: partition | pack W (512 thr/task) | combine
#define NB_PACK 64                    // 64*512 = 32768 frag elems
#define NB_COMB 2
#define NTASK_A (N_PARTS + NB_PACK + NB_COMB)   // 457

// phase B tasks: build bins | gemm 128-row tiles
#define NB_GEMM 391                   // ceil(50000/128)
#define NTASK_B (NBIN + NB_GEMM)      // 489

typedef __attribute__((ext_vector_type(8))) short bf16x8;   // MFMA A/B frag (4 VGPRs)
typedef __attribute__((ext_vector_type(4))) float f32x4;    // MFMA C/D frag
typedef __attribute__((ext_vector_type(2))) float f32x2;
typedef __attribute__((ext_vector_type(4))) int   i32x4;

__device__ __forceinline__ unsigned short f2bf(float f) {
    unsigned u = __builtin_bit_cast(unsigned, f);
    u += 0x7fff + ((u >> 16) & 1);          // round-to-nearest-even
    return (unsigned short)(u >> 16);
}
__device__ __forceinline__ float bflo(unsigned u) { return __builtin_bit_cast(float, u << 16); }
__device__ __forceinline__ float bfhi(unsigned u) { return __builtin_bit_cast(float, u & 0xffff0000u); }

// ---- fp8 e4m3 pack/unpack (HW cvt on gfx950; software fallback) ----
__device__ __forceinline__ unsigned char f2fp8_sw(float f) {
    unsigned u = __builtin_bit_cast(unsigned, f);
    unsigned s = (u >> 24) & 0x80;
    unsigned a = u & 0x7fffffffu;
    if (a < 0x3c800000u) return (unsigned char)s;          // |x| < 2^-6 -> +-0 (flush)
    if (a > 0x43e00000u) a = 0x43e00000u;                  // clamp to 448
    unsigned lsb = (a >> 20) & 1;
    a += 0x7ffffu + lsb;                                   // RNE to 3 mantissa bits
    unsigned e = (a >> 23) - 120;                          // e4m3 bias 7
    unsigned m = (a >> 20) & 7;
    return (unsigned char)(s | (e << 3) | m);
}
__device__ __forceinline__ float fp82f_sw(unsigned b) {
    unsigned s = (b & 0x80u) << 24;
    unsigned e = (b >> 3) & 15, m = b & 7;
    if (e == 0) {
        float v = (float)m * 0.001953125f;                 // m * 2^-9
        return (b & 0x80u) ? -v : v;
    }
    return __builtin_bit_cast(float, s | ((e + 120) << 23) | (m << 20));
}
__device__ __forceinline__ unsigned short pk_fp8(float a, float b) {
#if __has_builtin(__builtin_amdgcn_cvt_pk_fp8_f32)
    return (unsigned short)__builtin_amdgcn_cvt_pk_fp8_f32(a, b, 0u, false);
#else
    return (unsigned short)(f2fp8_sw(a) | ((unsigned)f2fp8_sw(b) << 8));
#endif
}
__device__ __forceinline__ f32x2 unpk_fp8(unsigned short v) {
#if __has_builtin(__builtin_amdgcn_cvt_pk_f32_fp8)
    return __builtin_amdgcn_cvt_pk_f32_fp8((unsigned)v, false);
#else
    f32x2 r; r[0] = fp82f_sw(v & 0xffu); r[1] = fp82f_sw(v >> 8); return r;
#endif
}

// ---------------- the whole pipeline as one cooperative kernel ----------------
__global__ __launch_bounds__(512) void k_all(const float* __restrict__ x,
                                             const int* __restrict__ src,
                                             const int* __restrict__ dst,
                                             const float* __restrict__ W1s,
                                             const float* __restrict__ W1n,
                                             const float* __restrict__ b1,
                                             const float* __restrict__ W2s,
                                             const float* __restrict__ W2n,
                                             const float* __restrict__ b2,
                                             const float* __restrict__ Wf,
                                             const float* __restrict__ bf,
                                             int* __restrict__ cnt,
                                             unsigned short* __restrict__ bucket,
                                             unsigned* __restrict__ seg,
                                             int* __restrict__ segcnt,
                                             unsigned short* __restrict__ zb,
                                             unsigned char* __restrict__ yb8,
                                             unsigned short* __restrict__ wpack,
                                             float* __restrict__ wc,
                                             float* __restrict__ pq,
                                             float* __restrict__ out) {
    cg::grid_group grid = cg::this_grid();
    __shared__ int smem[1024];         // partition: [0..97] hist | build: cur[512] + scnt[391]
    int blk = blockIdx.x;
    int G = gridDim.x;
    int tid = threadIdx.x;
    int wavein = tid >> 6;
    int lane = tid & 63;

    // ================= Phase A: partition | pack W | combine =================
    for (int task = blk; task < NTASK_A; task += G) {
        if (task < N_PARTS) {
            // ---- partition: 2048 edges read ONCE, binned by dst>>9 ----
            __syncthreads();
            for (int i = tid; i < NBIN; i += 512) smem[i] = 0;
            __syncthreads();
            int e0 = task * CHUNK_A + tid * 4;
            bool v = e0 < N_EDGES;                  // N_EDGES % 4 == 0: all-or-nothing
            i32x4 d4 = {0,0,0,0}, s4 = d4;
            if (v) {
                d4 = *(const i32x4*)(dst + e0);
                s4 = *(const i32x4*)(src + e0);
            }
#pragma unroll
            for (int j = 0; j < 4; ++j) {
                if (v) {
                    int b = (int)((unsigned)d4[j] >> 9);
                    int lpos = atomicAdd(&smem[b], 1);
                    if (lpos < NSLOT)
                        seg[((size_t)b * N_PARTS + task) * NSLOT + lpos] =
                            ((unsigned)d4[j] << 16) | (unsigned)s4[j];
                }
            }
            __syncthreads();
            for (int i = tid; i < NBIN; i += 512) {
                int h = smem[i];
                segcnt[i * N_PARTS + task] = h < NSLOT ? h : NSLOT;
            }
        } else if (task < N_PARTS + NB_PACK) {
            // wpack[((nt*8+ks)*64+ln)*8 + j] = Wcat[ks*32+(ln>>4)*8+j][nt*16+(ln&15)]
            int idx = (task - N_PARTS) * 512 + tid;   // 32768 total
            int j = idx & 7;
            int ln = (idx >> 3) & 63;
            int ks = (idx >> 9) & 7;
            int nt = idx >> 12;
            int krow = ks * 32 + ((ln >> 4) << 3) + j;
            int col = nt * 16 + (ln & 15);
            float v = (krow < 128) ? W1s[krow * 128 + col] : W1n[(krow - 128) * 128 + col];
            wpack[idx] = f2bf(v);
        } else {
            // wc[0..255]=Wcs[k][c], [256..511]=Wcn[k][c], [512..513]=bc
            int role = task - N_PARTS - NB_PACK;   // 0: Wcs, 1: Wcn + bc
            if (tid < 256) {
                int k = tid >> 1, c = tid & 1;
                const float* W = role == 0 ? W2s : W2n;
                float s = 0.f;
                for (int j = 0; j < 128; ++j) s += W[k * 128 + j] * Wf[j * 2 + c];
                wc[role * 256 + k * 2 + c] = s;
                if (role == 1 && tid < 2) {
                    float sb = bf[tid];
                    for (int j = 0; j < 128; ++j) sb += b2[j] * Wf[j * 2 + tid];
                    wc[512 + tid] = sb;
                }
            }
        }
    }
    grid.sync();

    // ================= Phase B: bin build || z,y GEMM =================
    for (int task = blk; task < NTASK_B; task += G) {
        if (task < NBIN) {
            // ---- build bin: LDS cursors, 8 waves, batch-4 loads ----
            int b = task;                         // blk==task first pass -> blk%8==b%8 (L2 home)
            int* cur = smem;
            int* scnt = smem + BIN_SZ;
            __syncthreads();
            for (int i = tid; i < BIN_SZ; i += 512) cur[i] = 0;
            for (int i = tid; i < N_PARTS; i += 512) scnt[i] = segcnt[b * N_PARTS + i];
            __syncthreads();
            const unsigned* segb = seg + (size_t)b * N_PARTS * NSLOT;
            for (int j = 0; j < 13; ++j) {
                unsigned v[4];
#pragma unroll
                for (int t = 0; t < 4; ++t) {
                    int p = wavein + 8 * (j * 4 + t);
                    int n = p < N_PARTS ? scnt[p] : 0;
                    v[t] = lane < n ? segb[(size_t)p * NSLOT + lane] : 0xffffffffu;
                }
#pragma unroll
                for (int t = 0; t < 4; ++t) {
                    if (v[t] != 0xffffffffu) {
                        int d = (int)(v[t] >> 16);
                        int p = atomicAdd(&cur[d & (BIN_SZ - 1)], 1);
                        if (p < CAP) bucket[(size_t)d * CAP + p] = (unsigned short)(v[t] & 0xffffu);
                    }
                }
            }
            __syncthreads();
            for (int i = tid; i < BIN_SZ; i += 512) {
                int node = (b << 9) + i;
                if (node < N_NODES) cnt[node] = cur[i];
            }
        } else {
            // ---- dense GEMM: 128-row tile, z = x@W1s+b1 (bf16), y = x@W1n (fp8) ----
            int g4 = task - NBIN;
            int l15 = lane & 15;
            int rowBase = g4 * 128 + wavein * 16;
            int arow = rowBase + l15;
            if (arow >= N_NODES) arow = N_NODES - 1;   // tail clamp; stores guarded
            int koff = (lane >> 4) << 3;

            const float* xrow = x + (size_t)arow * 128 + koff;   // x is L3-resident
            bf16x8 a[4];
#pragma unroll
            for (int ks = 0; ks < 4; ++ks) {
                f32x4 f0 = *(const f32x4*)(xrow + ks * 32);
                f32x4 f1 = *(const f32x4*)(xrow + ks * 32 + 4);
                bf16x8 t;
                t[0] = (short)f2bf(f0[0]); t[1] = (short)f2bf(f0[1]);
                t[2] = (short)f2bf(f0[2]); t[3] = (short)f2bf(f0[3]);
                t[4] = (short)f2bf(f1[0]); t[5] = (short)f2bf(f1[1]);
                t[6] = (short)f2bf(f1[2]); t[7] = (short)f2bf(f1[3]);
                a[ks] = t;
            }

            f32x4 zacc[8] = {};
            f32x4 yacc[8] = {};
            const bf16x8* wp = (const bf16x8*)wpack + lane;
            __builtin_amdgcn_s_setprio(1);
#pragma unroll
            for (int nt = 0; nt < 8; ++nt) {
#pragma unroll
                for (int ks = 0; ks < 4; ++ks)
                    zacc[nt] = __builtin_amdgcn_mfma_f32_16x16x32_bf16(a[ks], wp[(nt * 8 + ks) * 64], zacc[nt], 0, 0, 0);
#pragma unroll
                for (int ks = 0; ks < 4; ++ks)
                    yacc[nt] = __builtin_amdgcn_mfma_f32_16x16x32_bf16(a[ks], wp[(nt * 8 + 4 + ks) * 64], yacc[nt], 0, 0, 0);
            }
            __builtin_amdgcn_s_setprio(0);

            // C/D layout: col = lane&15, row = (lane>>4)*4 + reg
            // paired-column store: pair p2 = k*16+l15 -> cols (32k+l15, 32k+16+l15)
            int crow0 = rowBase + ((lane >> 4) << 2);
#pragma unroll
            for (int k = 0; k < 4; ++k) {
                int colA = k * 32 + l15;
                float biasA = b1[colA];
                float biasB = b1[colA + 16];
                int p2 = k * 16 + l15;
#pragma unroll
                for (int r = 0; r < 4; ++r) {
                    int row = crow0 + r;
                    if (row < N_NODES) {
                        unsigned zu = (unsigned)f2bf(zacc[2 * k][r] + biasA) |
                                      ((unsigned)f2bf(zacc[2 * k + 1][r] + biasB) << 16);
                        *(unsigned*)(zb + (size_t)row * 128 + 2 * p2) = zu;
                        *(unsigned short*)(yb8 + (size_t)row * 128 + 2 * p2) =
                            pk_fp8(yacc[2 * k][r], yacc[2 * k + 1][r]);
                    }
                }
            }
        }
    }
    grid.sync();

    // ================= Phase C: h1 = relu(z + mean_neigh(y)); pq = {h1@Wcs, h1@Wcn} =================
    {
        int xcd = blk & 7;
        int wstride = (G >> 3) * 8;
        for (int i = (blk >> 3) * 8 + wavein; i < 13 * 512; i += wstride) {
            int b = xcd + ((i >> 9) << 3);          // bin; bin%8==xcd matches build homing
            if (b >= NBIN) break;
            int node = (b << 9) + (i & 511);
            if (node >= N_NODES) continue;

            int deg = cnt[node];
            int colA = ((lane >> 4) << 5) + (lane & 15);
            int colB = colA + 16;
            unsigned zu = *(const unsigned*)(zb + (size_t)node * 128 + 2 * lane);
            float2 wsA = *(const float2*)(wc + 2 * colA);
            float2 wsB = *(const float2*)(wc + 2 * colB);
            float2 wnA = *(const float2*)(wc + 256 + 2 * colA);
            float2 wnB = *(const float2*)(wc + 256 + 2 * colB);

            int n = deg < CAP ? deg : CAP;
            const unsigned short* bk = bucket + (size_t)node * CAP;
            const unsigned char* ybl = yb8 + 2 * lane;
            float ax0 = 0.f, ay0 = 0.f, ax1 = 0.f, ay1 = 0.f;
            float ax2 = 0.f, ay2 = 0.f, ax3 = 0.f, ay3 = 0.f;
            int e = 0;
            for (; e + 16 <= n; e += 16) {
                uint4 ia = *(const uint4*)(bk + e);
                uint4 ib = *(const uint4*)(bk + e + 8);
                int s0  = ia.x & 0xffff, s1  = ia.x >> 16, s2  = ia.y & 0xffff, s3  = ia.y >> 16;
                int s4  = ia.z & 0xffff, s5  = ia.z >> 16, s6  = ia.w & 0xffff, s7  = ia.w >> 16;
                int s8  = ib.x & 0xffff, s9  = ib.x >> 16, s10 = ib.y & 0xffff, s11 = ib.y >> 16;
                int s12 = ib.z & 0xffff, s13 = ib.z >> 16, s14 = ib.w & 0xffff, s15 = ib.w >> 16;
                unsigned short t0  = *(const unsigned short*)(ybl + (size_t)s0  * 128);
                unsigned short t1  = *(const unsigned short*)(ybl + (size_t)s1  * 128);
                unsigned short t2  = *(const unsigned short*)(ybl + (size_t)s2  * 128);
                unsigned short t3  = *(const unsigned short*)(ybl + (size_t)s3  * 128);
                unsigned short t4  = *(const unsigned short*)(ybl + (size_t)s4  * 128);
                unsigned short t5  = *(const unsigned short*)(ybl + (size_t)s5  * 128);
                unsigned short t6  = *(const unsigned short*)(ybl + (size_t)s6  * 128);
                unsigned short t7  = *(const unsigned short*)(ybl + (size_t)s7  * 128);
                unsigned short t8  = *(const unsigned short*)(ybl + (size_t)s8  * 128);
                unsigned short t9  = *(const unsigned short*)(ybl + (size_t)s9  * 128);
                unsigned short t10 = *(const unsigned short*)(ybl + (size_t)s10 * 128);
                unsigned short t11 = *(const unsigned short*)(ybl + (size_t)s11 * 128);
                unsigned short t12 = *(const unsigned short*)(ybl + (size_t)s12 * 128);
                unsigned short t13 = *(const unsigned short*)(ybl + (size_t)s13 * 128);
                unsigned short t14 = *(const unsigned short*)(ybl + (size_t)s14 * 128);
                unsigned short t15 = *(const unsigned short*)(ybl + (size_t)s15 * 128);
                f32x2 v0 = unpk_fp8(t0),  v1 = unpk_fp8(t1),  v2 = unpk_fp8(t2),  v3 = unpk_fp8(t3);
                f32x2 v4 = unpk_fp8(t4),  v5 = unpk_fp8(t5),  v6 = unpk_fp8(t6),  v7 = unpk_fp8(t7);
                f32x2 v8 = unpk_fp8(t8),  v9 = unpk_fp8(t9),  v10 = unpk_fp8(t10), v11 = unpk_fp8(t11);
                f32x2 v12 = unpk_fp8(t12), v13 = unpk_fp8(t13), v14 = unpk_fp8(t14), v15 = unpk_fp8(t15);
                ax0 += v0[0];  ay0 += v0[1];  ax1 += v1[0];  ay1 += v1[1];
                ax2 += v2[0];  ay2 += v2[1];  ax3 += v3[0];  ay3 += v3[1];
                ax0 += v4[0];  ay0 += v4[1];  ax1 += v5[0];  ay1 += v5[1];
                ax2 += v6[0];  ay2 += v6[1];  ax3 += v7[0];  ay3 += v7[1];
                ax0 += v8[0];  ay0 += v8[1];  ax1 += v9[0];  ay1 += v9[1];
                ax2 += v10[0]; ay2 += v10[1]; ax3 += v11[0]; ay3 += v11[1];
                ax0 += v12[0]; ay0 += v12[1]; ax1 += v13[0]; ay1 += v13[1];
                ax2 += v14[0]; ay2 += v14[1]; ax3 += v15[0]; ay3 += v15[1];
            }
            if (e + 8 <= n) {
                uint4 ia = *(const uint4*)(bk + e);
                int s0 = ia.x & 0xffff, s1 = ia.x >> 16, s2 = ia.y & 0xffff, s3 = ia.y >> 16;
                int s4 = ia.z & 0xffff, s5 = ia.z >> 16, s6 = ia.w & 0xffff, s7 = ia.w >> 16;
                unsigned short t0 = *(const unsigned short*)(ybl + (size_t)s0 * 128);
                unsigned short t1 = *(const unsigned short*)(ybl + (size_t)s1 * 128);
                unsigned short t2 = *(const unsigned short*)(ybl + (size_t)s2 * 128);
                unsigned short t3 = *(const unsigned short*)(ybl + (size_t)s3 * 128);
                unsigned short t4 = *(const unsigned short*)(ybl + (size_t)s4 * 128);
                unsigned short t5 = *(const unsigned short*)(ybl + (size_t)s5 * 128);
                unsigned short t6 = *(const unsigned short*)(ybl + (size_t)s6 * 128);
                unsigned short t7 = *(const unsigned short*)(ybl + (size_t)s7 * 128);
                f32x2 v0 = unpk_fp8(t0), v1 = unpk_fp8(t1), v2 = unpk_fp8(t2), v3 = unpk_fp8(t3);
                f32x2 v4 = unpk_fp8(t4), v5 = unpk_fp8(t5), v6 = unpk_fp8(t6), v7 = unpk_fp8(t7);
                ax0 += v0[0]; ay0 += v0[1]; ax1 += v1[0]; ay1 += v1[1];
                ax2 += v2[0]; ay2 += v2[1]; ax3 += v3[0]; ay3 += v3[1];
                ax0 += v4[0]; ay0 += v4[1]; ax1 += v5[0]; ay1 += v5[1];
                ax2 += v6[0]; ay2 += v6[1]; ax3 += v7[0]; ay3 += v7[1];
                e += 8;
            }
            if (e + 4 <= n) {
                uint2 ia = *(const uint2*)(bk + e);
                int s0 = ia.x & 0xffff, s1 = ia.x >> 16, s2 = ia.y & 0xffff, s3 = ia.y >> 16;
                unsigned short t0 = *(const unsigned short*)(ybl + (size_t)s0 * 128);
                unsigned short t1 = *(const unsigned short*)(ybl + (size_t)s1 * 128);
                unsigned short t2 = *(const unsigned short*)(ybl + (size_t)s2 * 128);
                unsigned short t3 = *(const unsigned short*)(ybl + (size_t)s3 * 128);
                f32x2 v0 = unpk_fp8(t0), v1 = unpk_fp8(t1), v2 = unpk_fp8(t2), v3 = unpk_fp8(t3);
                ax0 += v0[0]; ay0 += v0[1]; ax1 += v1[0]; ay1 += v1[1];
                ax2 += v2[0]; ay2 += v2[1]; ax3 += v3[0]; ay3 += v3[1];
                e += 4;
            }
            for (; e < n; ++e) {
                unsigned short t = *(const unsigned short*)(ybl + (size_t)bk[e] * 128);
                f32x2 v = unpk_fp8(t);
                ax0 += v[0]; ay0 += v[1];
            }
            float inv = 1.0f / fmaxf((float)deg, 1.0f);
            float mx = ((ax0 + ax1) + (ax2 + ax3)) * inv;
            float my = ((ay0 + ay1) + (ay2 + ay3)) * inv;

            float h0 = fmaxf(bflo(zu) + mx, 0.f);
            float h1v = fmaxf(bfhi(zu) + my, 0.f);

            float p0 = h0 * wsA.x + h1v * wsB.x;
            float p1 = h0 * wsA.y + h1v * wsB.y;
            float q0 = h0 * wnA.x + h1v * wnB.x;
            float q1 = h0 * wnA.y + h1v * wnB.y;
#pragma unroll
            for (int off = 32; off >= 1; off >>= 1) {
                p0 += __shfl_xor(p0, off, 64);
                p1 += __shfl_xor(p1, off, 64);
                q0 += __shfl_xor(q0, off, 64);
                q1 += __shfl_xor(q1, off, 64);
            }
            if (lane == 0) {
                float4 o; o.x = p0; o.y = p1; o.z = q0; o.w = q1;
                ((float4*)pq)[node] = o;
            }
        }
    }
    grid.sync();

    // ================= Phase D: out[n] = pq[n].p + mean_src(pq[src].q) + bc =================
    {
        int xcd = blk & 7;
        int wstride = (G >> 3) * 8;
        float bc0 = wc[512], bc1 = wc[513];
        for (int i = (blk >> 3) * 8 + wavein; i < 13 * 512; i += wstride) {
            int b = xcd + ((i >> 9) << 3);
            if (b >= NBIN) break;
            int node = (b << 9) + (i & 511);
            if (node >= N_NODES) continue;

            int deg = cnt[node];
            int n = deg < CAP ? deg : CAP;
            float qx = 0.f, qy = 0.f;
            if (lane < n) {
                int s = bucket[(size_t)node * CAP + lane];
                float2 q = *(const float2*)(pq + (size_t)s * 4 + 2);
                qx = q.x; qy = q.y;
            }
#pragma unroll
            for (int off = 32; off >= 1; off >>= 1) {
                qx += __shfl_xor(qx, off, 64);
                qy += __shfl_xor(qy, off, 64);
            }
            if (lane == 0) {
                float inv = 1.0f / fmaxf((float)deg, 1.0f);
                float2 p = *(const float2*)(pq + (size_t)node * 4);
                out[(size_t)node * 2 + 0] = p.x + qx * inv + bc0;
                out[(size_t)node * 2 + 1] = p.y + qy * inv + bc1;
            }
        }
    }
}

extern "C" void kernel_launch(void* const* d_in, const int* in_sizes, int n_in,
                              void* d_out, int out_size, void* d_ws, size_t ws_size,
                              hipStream_t stream) {
    const float* x   = (const float*)d_in[0];
    const int* esrc  = (const int*)d_in[1];
    const int* edst  = (const int*)d_in[2];
    const float* W1s = (const float*)d_in[3];
    const float* W1n = (const float*)d_in[4];
    const float* b1  = (const float*)d_in[5];
    const float* W2s = (const float*)d_in[6];
    const float* W2n = (const float*)d_in[7];
    const float* b2  = (const float*)d_in[8];
    const float* Wf  = (const float*)d_in[9];
    const float* bf  = (const float*)d_in[10];
    float* out = (float*)d_out;

    char* ws = (char*)d_ws;
    auto alloc = [&](size_t bytes) {
        char* p = ws;
        ws += (bytes + 255) & ~(size_t)255;
        return p;
    };
    int*            cnt    = (int*)           alloc((size_t)N_NODES * 4);
    unsigned short* bucket = (unsigned short*)alloc((size_t)N_NODES * CAP * 2);
    unsigned*       seg    = (unsigned*)      alloc((size_t)NBIN * N_PARTS * NSLOT * 4);
    int*            segcnt = (int*)           alloc((size_t)NBIN * N_PARTS * 4);
    unsigned short* zb     = (unsigned short*)alloc((size_t)N_NODES * 128 * 2);
    unsigned char*  yb8    = (unsigned char*) alloc((size_t)N_NODES * 128);
    unsigned short* wpack  = (unsigned short*)alloc(8 * 8 * 64 * 8 * 2);
    float*          pq     = (float*)         alloc((size_t)N_NODES * 4 * 4);
    float*          wc     = (float*)         alloc(1024 * 4);

    int nb = 0;
    hipOccupancyMaxActiveBlocksPerMultiprocessor(&nb, (const void*)k_all, 512, 0);
    if (nb < 1) nb = 1;
    int G = nb * 256;
    if (G > 1024) G = 1024;

    void* kargs[] = {
        (void*)&x, (void*)&esrc, (void*)&edst, (void*)&W1s, (void*)&W1n, (void*)&b1,
        (void*)&W2s, (void*)&W2n, (void*)&b2, (void*)&Wf, (void*)&bf,
        (void*)&cnt, (void*)&bucket, (void*)&seg, (void*)&segcnt,
        (void*)&zb, (void*)&yb8, (void*)&wpack, (void*)&wc, (void*)&pq, (void*)&out
    };
    hipLaunchCooperativeKernel((void*)k_all, dim3(G), dim3(512), kargs, 0, stream);
}

// Round 16
// 104.627 us; speedup vs baseline: 2.4256x; 2.4256x over previous
//
#include <hip/hip_runtime.h>
#include <cstdint>
#include <cstddef>

#define N_NODES 50000
#define N_EDGES 800000
#define CAP 64        // max in-degree; Poisson(16): P(>64) astronomically small

#define BIN_SZ 512                    // nodes per bin (pow2: bin = dst>>9)
#define NBIN 98                       // ceil(50000/512)
#define NSLOT 64                      // per-(bin,part) slot; Binom(2048,.0102) mean 21, +9.5 sigma

#define CHUNK_A 2048
#define N_PARTS 391                   // 391*2048 = 800768 >= 800000

// K1 (front): pairs of blocks = {partition g} {gemm g}, then 2 combine blocks
#define NB_GEMM 391                   // 128-row tiles (391*128 = 50048 >= 50000)
#define NB_FRONT (2 * N_PARTS + 2)    // 784

// K2 (build): one block per bin; blk == bin -> blk%8 == bin%8 (L2 homing)
#define NB_BUILD NBIN

// K3/K4: xcd = blk&7; i = (blk>>3)*4+wavein; b = xcd + 8*(i>>9); node = b*512 + (i&511)
#define NB_AGG 13312                  // 8 * 1664

typedef __attribute__((ext_vector_type(8))) short bf16x8;   // MFMA A/B frag (4 VGPRs)
typedef __attribute__((ext_vector_type(4))) float f32x4;    // MFMA C/D frag
typedef __attribute__((ext_vector_type(2))) float f32x2;
typedef __attribute__((ext_vector_type(4))) int   i32x4;

__device__ __forceinline__ unsigned short f2bf(float f) {
    unsigned u = __builtin_bit_cast(unsigned, f);
    u += 0x7fff + ((u >> 16) & 1);          // round-to-nearest-even
    return (unsigned short)(u >> 16);
}
__device__ __forceinline__ float bflo(unsigned u) { return __builtin_bit_cast(float, u << 16); }
__device__ __forceinline__ float bfhi(unsigned u) { return __builtin_bit_cast(float, u & 0xffff0000u); }

// ---- fp8 e4m3 pack/unpack (HW cvt on gfx950; software fallback) ----
__device__ __forceinline__ unsigned char f2fp8_sw(float f) {
    unsigned u = __builtin_bit_cast(unsigned, f);
    unsigned s = (u >> 24) & 0x80;
    unsigned a = u & 0x7fffffffu;
    if (a < 0x3c800000u) return (unsigned char)s;          // |x| < 2^-6 -> +-0 (flush)
    if (a > 0x43e00000u) a = 0x43e00000u;                  // clamp to 448
    unsigned lsb = (a >> 20) & 1;
    a += 0x7ffffu + lsb;                                   // RNE to 3 mantissa bits
    unsigned e = (a >> 23) - 120;                          // e4m3 bias 7
    unsigned m = (a >> 20) & 7;
    return (unsigned char)(s | (e << 3) | m);
}
__device__ __forceinline__ float fp82f_sw(unsigned b) {
    unsigned s = (b & 0x80u) << 24;
    unsigned e = (b >> 3) & 15, m = b & 7;
    if (e == 0) {
        float v = (float)m * 0.001953125f;                 // m * 2^-9
        return (b & 0x80u) ? -v : v;
    }
    return __builtin_bit_cast(float, s | ((e + 120) << 23) | (m << 20));
}
__device__ __forceinline__ unsigned short pk_fp8(float a, float b) {
#if __has_builtin(__builtin_amdgcn_cvt_pk_fp8_f32)
    return (unsigned short)__builtin_amdgcn_cvt_pk_fp8_f32(a, b, 0u, false);
#else
    return (unsigned short)(f2fp8_sw(a) | ((unsigned)f2fp8_sw(b) << 8));
#endif
}
__device__ __forceinline__ f32x2 unpk_fp8(unsigned short v) {
#if __has_builtin(__builtin_amdgcn_cvt_pk_f32_fp8)
    return __builtin_amdgcn_cvt_pk_f32_fp8((unsigned)v, false);
#else
    f32x2 r; r[0] = fp82f_sw(v & 0xffu); r[1] = fp82f_sw(v >> 8); return r;
#endif
}

// ---------------- K1: {edge partition} || {z,y GEMM w/ LDS self-packed W} || {combine} ----------------
__global__ __launch_bounds__(512) void k_front(const float* __restrict__ x,
                                               const int* __restrict__ src,
                                               const int* __restrict__ dst,
                                               const float* __restrict__ W1s,
                                               const float* __restrict__ W1n,
                                               const float* __restrict__ b1,
                                               const float* __restrict__ W2s,
                                               const float* __restrict__ W2n,
                                               const float* __restrict__ b2,
                                               const float* __restrict__ Wf,
                                               const float* __restrict__ bf,
                                               unsigned* __restrict__ seg,
                                               int* __restrict__ segcnt,
                                               unsigned short* __restrict__ zb,
                                               unsigned char* __restrict__ yb8,
                                               float* __restrict__ wc) {
    __shared__ short wlds[32768];      // gemm: 64 KB frag-packed W | partition: hist[] overlay
    int blk = blockIdx.x;
    int tid = threadIdx.x;

    if (blk < 2 * N_PARTS && (blk & 1) == 0) {
        // ---- partition task g = blk>>1: 2048 edges read ONCE, binned by dst>>9 ----
        int g = blk >> 1;
        int* hist = (int*)wlds;
        for (int i = tid; i < NBIN; i += 512) hist[i] = 0;
        __syncthreads();
        int e0 = g * CHUNK_A + tid * 4;
        bool v = e0 < N_EDGES;                    // N_EDGES % 4 == 0: all-or-nothing
        i32x4 d4 = {0,0,0,0}, s4 = d4;
        if (v) {
            d4 = *(const i32x4*)(dst + e0);
            s4 = *(const i32x4*)(src + e0);
        }
#pragma unroll
        for (int j = 0; j < 4; ++j) {
            if (v) {
                int b = (int)((unsigned)d4[j] >> 9);
                int lpos = atomicAdd(&hist[b], 1);
                if (lpos < NSLOT)
                    seg[((size_t)b * N_PARTS + g) * NSLOT + lpos] =
                        ((unsigned)d4[j] << 16) | (unsigned)s4[j];
            }
        }
        __syncthreads();
        for (int i = tid; i < NBIN; i += 512) {
            int h = hist[i];
            segcnt[i * N_PARTS + g] = h < NSLOT ? h : NSLOT;
        }
    } else if (blk < 2 * N_PARTS) {
        // ---- gemm task g = blk>>1: self-pack W into LDS, then 128-row tile ----
        int g4 = blk >> 1;
        // pack: wlds[((nt*8+ks)*64+ln)*8 + j] = Wcat[ks*32+(ln>>4)*8+j][nt*16+(ln&15)]
        for (int i = 0; i < 64; ++i) {
            int idx = i * 512 + tid;               // 32768 total
            int j = idx & 7;
            int ln = (idx >> 3) & 63;
            int ks = (idx >> 9) & 7;
            int nt = idx >> 12;
            int krow = ks * 32 + ((ln >> 4) << 3) + j;
            int col = nt * 16 + (ln & 15);
            float v = (krow < 128) ? W1s[krow * 128 + col] : W1n[(krow - 128) * 128 + col];
            wlds[idx] = (short)f2bf(v);
        }
        __syncthreads();

        int wavein = tid >> 6;
        int lane = tid & 63;
        int l15 = lane & 15;
        int rowBase = g4 * 128 + wavein * 16;
        int arow = rowBase + l15;
        if (arow >= N_NODES) arow = N_NODES - 1;   // tail clamp; stores guarded
        int koff = (lane >> 4) << 3;

        const float* xrow = x + (size_t)arow * 128 + koff;
        bf16x8 a[4];
#pragma unroll
        for (int ks = 0; ks < 4; ++ks) {
            f32x4 f0 = *(const f32x4*)(xrow + ks * 32);
            f32x4 f1 = *(const f32x4*)(xrow + ks * 32 + 4);
            bf16x8 t;
            t[0] = (short)f2bf(f0[0]); t[1] = (short)f2bf(f0[1]);
            t[2] = (short)f2bf(f0[2]); t[3] = (short)f2bf(f0[3]);
            t[4] = (short)f2bf(f1[0]); t[5] = (short)f2bf(f1[1]);
            t[6] = (short)f2bf(f1[2]); t[7] = (short)f2bf(f1[3]);
            a[ks] = t;
        }

        f32x4 zacc[8] = {};
        f32x4 yacc[8] = {};
        const bf16x8* wp = (const bf16x8*)wlds + lane;
        __builtin_amdgcn_s_setprio(1);
#pragma unroll
        for (int nt = 0; nt < 8; ++nt) {
#pragma unroll
            for (int ks = 0; ks < 4; ++ks)
                zacc[nt] = __builtin_amdgcn_mfma_f32_16x16x32_bf16(a[ks], wp[(nt * 8 + ks) * 64], zacc[nt], 0, 0, 0);
#pragma unroll
            for (int ks = 0; ks < 4; ++ks)
                yacc[nt] = __builtin_amdgcn_mfma_f32_16x16x32_bf16(a[ks], wp[(nt * 8 + 4 + ks) * 64], yacc[nt], 0, 0, 0);
        }
        __builtin_amdgcn_s_setprio(0);

        // C/D layout: col = lane&15, row = (lane>>4)*4 + reg
        // paired-column store: pair p2 = k*16+l15 -> cols (32k+l15, 32k+16+l15)
        int crow0 = rowBase + ((lane >> 4) << 2);
#pragma unroll
        for (int k = 0; k < 4; ++k) {
            int colA = k * 32 + l15;
            float biasA = b1[colA];
            float biasB = b1[colA + 16];
            int p2 = k * 16 + l15;
#pragma unroll
            for (int r = 0; r < 4; ++r) {
                int row = crow0 + r;
                if (row < N_NODES) {
                    unsigned zu = (unsigned)f2bf(zacc[2 * k][r] + biasA) |
                                  ((unsigned)f2bf(zacc[2 * k + 1][r] + biasB) << 16);
                    *(unsigned*)(zb + (size_t)row * 128 + 2 * p2) = zu;
                    *(unsigned short*)(yb8 + (size_t)row * 128 + 2 * p2) =
                        pk_fp8(yacc[2 * k][r], yacc[2 * k + 1][r]);
                }
            }
        }
    } else {
        // ---- combine: wc[0..255]=Wcs[k][c], [256..511]=Wcn[k][c], [512..513]=bc ----
        int role = blk - 2 * N_PARTS;   // 0: Wcs, 1: Wcn + bc
        if (tid < 256) {
            int k = tid >> 1, c = tid & 1;
            const float* W = role == 0 ? W2s : W2n;
            float s = 0.f;
            for (int j = 0; j < 128; ++j) s += W[k * 128 + j] * Wf[j * 2 + c];
            wc[role * 256 + k * 2 + c] = s;
            if (role == 1 && tid < 2) {
                float sb = bf[tid];
                for (int j = 0; j < 128; ++j) sb += b2[j] * Wf[j * 2 + tid];
                wc[512 + tid] = sb;
            }
        }
    }
}

// ---------------- K2: atomic-free bin build (one wide block per bin) ----------------
__global__ __launch_bounds__(512) void k_build(const unsigned* __restrict__ seg,
                                               const int* __restrict__ segcnt,
                                               int* __restrict__ cnt,
                                               unsigned short* __restrict__ bucket) {
    int b = blockIdx.x;                  // blk == bin -> blk%8 == bin%8 (L2 homing)
    int tid = threadIdx.x;
    __shared__ int cur[BIN_SZ];
    __shared__ int scnt[N_PARTS];
    for (int i = tid; i < BIN_SZ; i += 512) cur[i] = 0;
    for (int i = tid; i < N_PARTS; i += 512) scnt[i] = segcnt[b * N_PARTS + i];
    __syncthreads();
    int wave = tid >> 6, lane = tid & 63;
    const unsigned* segb = seg + (size_t)b * N_PARTS * NSLOT;
    // wave w owns parts w, w+8, ... (49 parts); batches of 4 -> 13 latency steps
    for (int j = 0; j < 13; ++j) {
        unsigned v[4];
#pragma unroll
        for (int t = 0; t < 4; ++t) {
            int p = wave + 8 * (j * 4 + t);
            int n = p < N_PARTS ? scnt[p] : 0;
            v[t] = lane < n ? segb[(size_t)p * NSLOT + lane] : 0xffffffffu;
        }
#pragma unroll
        for (int t = 0; t < 4; ++t) {
            if (v[t] != 0xffffffffu) {
                int d = (int)(v[t] >> 16);
                int p = atomicAdd(&cur[d & (BIN_SZ - 1)], 1);
                if (p < CAP) bucket[(size_t)d * CAP + p] = (unsigned short)(v[t] & 0xffffu);
            }
        }
    }
    __syncthreads();
    for (int i = tid; i < BIN_SZ; i += 512) {
        int node = (b << 9) + i;
        if (node < N_NODES) cnt[node] = cur[i];
    }
}

// ---------------- K3: h1 = relu(z + mean_neigh(y)); pq = {h1@Wcs, h1@Wcn} ----------------
__global__ __launch_bounds__(256) void k_agg2(const unsigned char* __restrict__ yb8,
                                              const unsigned short* __restrict__ zb,
                                              const int* __restrict__ cnt,
                                              const unsigned short* __restrict__ bucket,
                                              const float* __restrict__ wc,
                                              float* __restrict__ pq) {
    int blk = blockIdx.x;
    int wavein = threadIdx.x >> 6;
    int lane = threadIdx.x & 63;
    int xcd = blk & 7;
    int i = (blk >> 3) * 4 + wavein;            // node-in-xcd
    int b = xcd + ((i >> 9) << 3);              // bin; bin%8==xcd matches build homing
    if (b >= NBIN) return;
    int node = (b << 9) + (i & 511);
    if (node >= N_NODES) return;

    int deg = cnt[node];
    int colA = ((lane >> 4) << 5) + (lane & 15);
    int colB = colA + 16;
    unsigned zu = *(const unsigned*)(zb + (size_t)node * 128 + 2 * lane);
    float2 wsA = *(const float2*)(wc + 2 * colA);
    float2 wsB = *(const float2*)(wc + 2 * colB);
    float2 wnA = *(const float2*)(wc + 256 + 2 * colA);
    float2 wnB = *(const float2*)(wc + 256 + 2 * colB);

    int n = deg < CAP ? deg : CAP;
    const unsigned short* bk = bucket + (size_t)node * CAP;
    const unsigned char* ybl = yb8 + 2 * lane;
    float ax0 = 0.f, ay0 = 0.f, ax1 = 0.f, ay1 = 0.f;
    float ax2 = 0.f, ay2 = 0.f, ax3 = 0.f, ay3 = 0.f;
    int e = 0;
    for (; e + 16 <= n; e += 16) {
        uint4 ia = *(const uint4*)(bk + e);       // 8 packed ushort indices
        uint4 ib = *(const uint4*)(bk + e + 8);
        int s0  = ia.x & 0xffff, s1  = ia.x >> 16, s2  = ia.y & 0xffff, s3  = ia.y >> 16;
        int s4  = ia.z & 0xffff, s5  = ia.z >> 16, s6  = ia.w & 0xffff, s7  = ia.w >> 16;
        int s8  = ib.x & 0xffff, s9  = ib.x >> 16, s10 = ib.y & 0xffff, s11 = ib.y >> 16;
        int s12 = ib.z & 0xffff, s13 = ib.z >> 16, s14 = ib.w & 0xffff, s15 = ib.w >> 16;
        unsigned short t0  = *(const unsigned short*)(ybl + (size_t)s0  * 128);
        unsigned short t1  = *(const unsigned short*)(ybl + (size_t)s1  * 128);
        unsigned short t2  = *(const unsigned short*)(ybl + (size_t)s2  * 128);
        unsigned short t3  = *(const unsigned short*)(ybl + (size_t)s3  * 128);
        unsigned short t4  = *(const unsigned short*)(ybl + (size_t)s4  * 128);
        unsigned short t5  = *(const unsigned short*)(ybl + (size_t)s5  * 128);
        unsigned short t6  = *(const unsigned short*)(ybl + (size_t)s6  * 128);
        unsigned short t7  = *(const unsigned short*)(ybl + (size_t)s7  * 128);
        unsigned short t8  = *(const unsigned short*)(ybl + (size_t)s8  * 128);
        unsigned short t9  = *(const unsigned short*)(ybl + (size_t)s9  * 128);
        unsigned short t10 = *(const unsigned short*)(ybl + (size_t)s10 * 128);
        unsigned short t11 = *(const unsigned short*)(ybl + (size_t)s11 * 128);
        unsigned short t12 = *(const unsigned short*)(ybl + (size_t)s12 * 128);
        unsigned short t13 = *(const unsigned short*)(ybl + (size_t)s13 * 128);
        unsigned short t14 = *(const unsigned short*)(ybl + (size_t)s14 * 128);
        unsigned short t15 = *(const unsigned short*)(ybl + (size_t)s15 * 128);
        f32x2 v0 = unpk_fp8(t0),  v1 = unpk_fp8(t1),  v2 = unpk_fp8(t2),  v3 = unpk_fp8(t3);
        f32x2 v4 = unpk_fp8(t4),  v5 = unpk_fp8(t5),  v6 = unpk_fp8(t6),  v7 = unpk_fp8(t7);
        f32x2 v8 = unpk_fp8(t8),  v9 = unpk_fp8(t9),  v10 = unpk_fp8(t10), v11 = unpk_fp8(t11);
        f32x2 v12 = unpk_fp8(t12), v13 = unpk_fp8(t13), v14 = unpk_fp8(t14), v15 = unpk_fp8(t15);
        ax0 += v0[0];  ay0 += v0[1];  ax1 += v1[0];  ay1 += v1[1];
        ax2 += v2[0];  ay2 += v2[1];  ax3 += v3[0];  ay3 += v3[1];
        ax0 += v4[0];  ay0 += v4[1];  ax1 += v5[0];  ay1 += v5[1];
        ax2 += v6[0];  ay2 += v6[1];  ax3 += v7[0];  ay3 += v7[1];
        ax0 += v8[0];  ay0 += v8[1];  ax1 += v9[0];  ay1 += v9[1];
        ax2 += v10[0]; ay2 += v10[1]; ax3 += v11[0]; ay3 += v11[1];
        ax0 += v12[0]; ay0 += v12[1]; ax1 += v13[0]; ay1 += v13[1];
        ax2 += v14[0]; ay2 += v14[1]; ax3 += v15[0]; ay3 += v15[1];
    }
    if (e + 8 <= n) {
        uint4 ia = *(const uint4*)(bk + e);
        int s0 = ia.x & 0xffff, s1 = ia.x >> 16, s2 = ia.y & 0xffff, s3 = ia.y >> 16;
        int s4 = ia.z & 0xffff, s5 = ia.z >> 16, s6 = ia.w & 0xffff, s7 = ia.w >> 16;
        unsigned short t0 = *(const unsigned short*)(ybl + (size_t)s0 * 128);
        unsigned short t1 = *(const unsigned short*)(ybl + (size_t)s1 * 128);
        unsigned short t2 = *(const unsigned short*)(ybl + (size_t)s2 * 128);
        unsigned short t3 = *(const unsigned short*)(ybl + (size_t)s3 * 128);
        unsigned short t4 = *(const unsigned short*)(ybl + (size_t)s4 * 128);
        unsigned short t5 = *(const unsigned short*)(ybl + (size_t)s5 * 128);
        unsigned short t6 = *(const unsigned short*)(ybl + (size_t)s6 * 128);
        unsigned short t7 = *(const unsigned short*)(ybl + (size_t)s7 * 128);
        f32x2 v0 = unpk_fp8(t0), v1 = unpk_fp8(t1), v2 = unpk_fp8(t2), v3 = unpk_fp8(t3);
        f32x2 v4 = unpk_fp8(t4), v5 = unpk_fp8(t5), v6 = unpk_fp8(t6), v7 = unpk_fp8(t7);
        ax0 += v0[0]; ay0 += v0[1]; ax1 += v1[0]; ay1 += v1[1];
        ax2 += v2[0]; ay2 += v2[1]; ax3 += v3[0]; ay3 += v3[1];
        ax0 += v4[0]; ay0 += v4[1]; ax1 += v5[0]; ay1 += v5[1];
        ax2 += v6[0]; ay2 += v6[1]; ax3 += v7[0]; ay3 += v7[1];
        e += 8;
    }
    if (e + 4 <= n) {
        uint2 ia = *(const uint2*)(bk + e);
        int s0 = ia.x & 0xffff, s1 = ia.x >> 16, s2 = ia.y & 0xffff, s3 = ia.y >> 16;
        unsigned short t0 = *(const unsigned short*)(ybl + (size_t)s0 * 128);
        unsigned short t1 = *(const unsigned short*)(ybl + (size_t)s1 * 128);
        unsigned short t2 = *(const unsigned short*)(ybl + (size_t)s2 * 128);
        unsigned short t3 = *(const unsigned short*)(ybl + (size_t)s3 * 128);
        f32x2 v0 = unpk_fp8(t0), v1 = unpk_fp8(t1), v2 = unpk_fp8(t2), v3 = unpk_fp8(t3);
        ax0 += v0[0]; ay0 += v0[1]; ax1 += v1[0]; ay1 += v1[1];
        ax2 += v2[0]; ay2 += v2[1]; ax3 += v3[0]; ay3 += v3[1];
        e += 4;
    }
    for (; e < n; ++e) {
        unsigned short t = *(const unsigned short*)(ybl + (size_t)bk[e] * 128);
        f32x2 v = unpk_fp8(t);
        ax0 += v[0]; ay0 += v[1];
    }
    float inv = 1.0f / fmaxf((float)deg, 1.0f);
    float mx = ((ax0 + ax1) + (ax2 + ax3)) * inv;
    float my = ((ay0 + ay1) + (ay2 + ay3)) * inv;

    float h0 = fmaxf(bflo(zu) + mx, 0.f);       // col colA
    float h1v = fmaxf(bfhi(zu) + my, 0.f);      // col colB

    float p0 = h0 * wsA.x + h1v * wsB.x;
    float p1 = h0 * wsA.y + h1v * wsB.y;
    float q0 = h0 * wnA.x + h1v * wnB.x;
    float q1 = h0 * wnA.y + h1v * wnB.y;
#pragma unroll
    for (int off = 32; off >= 1; off >>= 1) {
        p0 += __shfl_xor(p0, off, 64);
        p1 += __shfl_xor(p1, off, 64);
        q0 += __shfl_xor(q0, off, 64);
        q1 += __shfl_xor(q1, off, 64);
    }
    if (lane == 0) {
        float4 o; o.x = p0; o.y = p1; o.z = q0; o.w = q1;
        ((float4*)pq)[node] = o;
    }
}

// ---------------- K4: out[n] = pq[n].p + mean_src(pq[src].q) + bc ----------------
__global__ __launch_bounds__(256) void k_final(const float* __restrict__ pq,
                                               const int* __restrict__ cnt,
                                               const unsigned short* __restrict__ bucket,
                                               const float* __restrict__ wc,
                                               float* __restrict__ out) {
    int blk = blockIdx.x;
    int wavein = threadIdx.x >> 6;
    int lane = threadIdx.x & 63;
    int xcd = blk & 7;
    int i = (blk >> 3) * 4 + wavein;
    int b = xcd + ((i >> 9) << 3);
    if (b >= NBIN) return;
    int node = (b << 9) + (i & 511);
    if (node >= N_NODES) return;

    int deg = cnt[node];
    int n = deg < CAP ? deg : CAP;
    float qx = 0.f, qy = 0.f;
    if (lane < n) {
        int s = bucket[(size_t)node * CAP + lane];
        float2 q = *(const float2*)(pq + (size_t)s * 4 + 2);
        qx = q.x; qy = q.y;
    }
#pragma unroll
    for (int off = 32; off >= 1; off >>= 1) {
        qx += __shfl_xor(qx, off, 64);
        qy += __shfl_xor(qy, off, 64);
    }
    if (lane == 0) {
        float inv = 1.0f / fmaxf((float)deg, 1.0f);
        float2 p = *(const float2*)(pq + (size_t)node * 4);
        out[(size_t)node * 2 + 0] = p.x + qx * inv + wc[512];
        out[(size_t)node * 2 + 1] = p.y + qy * inv + wc[513];
    }
}

extern "C" void kernel_launch(void* const* d_in, const int* in_sizes, int n_in,
                              void* d_out, int out_size, void* d_ws, size_t ws_size,
                              hipStream_t stream) {
    const float* x   = (const float*)d_in[0];
    const int* esrc  = (const int*)d_in[1];
    const int* edst  = (const int*)d_in[2];
    const float* W1s = (const float*)d_in[3];
    const float* W1n = (const float*)d_in[4];
    const float* b1  = (const float*)d_in[5];
    const float* W2s = (const float*)d_in[6];
    const float* W2n = (const float*)d_in[7];
    const float* b2  = (const float*)d_in[8];
    const float* Wf  = (const float*)d_in[9];
    const float* bf  = (const float*)d_in[10];
    float* out = (float*)d_out;

    char* ws = (char*)d_ws;
    auto alloc = [&](size_t bytes) {
        char* p = ws;
        ws += (bytes + 255) & ~(size_t)255;
        return p;
    };
    int*            cnt    = (int*)           alloc((size_t)N_NODES * 4);
    unsigned short* bucket = (unsigned short*)alloc((size_t)N_NODES * CAP * 2);
    unsigned*       seg    = (unsigned*)      alloc((size_t)NBIN * N_PARTS * NSLOT * 4);
    int*            segcnt = (int*)           alloc((size_t)NBIN * N_PARTS * 4);
    unsigned short* zb     = (unsigned short*)alloc((size_t)N_NODES * 128 * 2);
    unsigned char*  yb8    = (unsigned char*) alloc((size_t)N_NODES * 128);
    float*          pq     = (float*)         alloc((size_t)N_NODES * 4 * 4);
    float*          wc     = (float*)         alloc(1024 * 4);

    k_front<<<NB_FRONT, 512, 0, stream>>>(x, esrc, edst, W1s, W1n, b1, W2s, W2n, b2, Wf, bf,
                                          seg, segcnt, zb, yb8, wc);
    k_build<<<NB_BUILD, 512, 0, stream>>>(seg, segcnt, cnt, bucket);
    k_agg2<<<NB_AGG, 256, 0, stream>>>(yb8, zb, cnt, bucket, wc, pq);
    k_final<<<NB_AGG, 256, 0, stream>>>(pq, cnt, bucket, wc, out);
}

// Round 17
// 99.467 us; speedup vs baseline: 2.5515x; 1.0519x over previous
//
#include <hip/hip_runtime.h>
#include <cstdint>
#include <cstddef>

#define N_NODES 50000
#define N_EDGES 800000
#define CAP 64        // max in-degree; Poisson(16): P(>64) astronomically small

#define BIN_SZ 512                    // nodes per bin (pow2: bin = dst>>9)
#define NBIN 98                       // ceil(50000/512)
#define NSLOT 64                      // per-(bin,part) slot; Binom(2048,.0102) mean 21, +9.5 sigma

#define CHUNK_A 2048
#define N_PARTS 391                   // 391*2048 = 800768 >= 800000

// K0: pack W (128 blocks x 256) + combine (2)
#define NB_PACK 128
#define NB_INIT (NB_PACK + 2)

// K1: interleaved {partition g} (even) | {gemm g} (odd), 512 thr
#define NB_GEMM 391                   // 128-row tiles (391*128 = 50048 >= 50000)
#define NB_PG (2 * N_PARTS)           // 782

// K2: build, one wide block per bin (blk == bin -> blk%8 == bin%8 L2 homing)
#define NB_BUILD NBIN

// K3/K4: xcd = blk&7; i = (blk>>3)*4+wavein; b = xcd + 8*(i>>9); node = b*512 + (i&511)
#define NB_AGG 13312                  // 8 * 1664

typedef __attribute__((ext_vector_type(8))) short bf16x8;   // MFMA A/B frag (4 VGPRs)
typedef __attribute__((ext_vector_type(4))) float f32x4;    // MFMA C/D frag
typedef __attribute__((ext_vector_type(2))) float f32x2;
typedef __attribute__((ext_vector_type(4))) int   i32x4;

__device__ __forceinline__ unsigned short f2bf(float f) {
    unsigned u = __builtin_bit_cast(unsigned, f);
    u += 0x7fff + ((u >> 16) & 1);          // round-to-nearest-even
    return (unsigned short)(u >> 16);
}
__device__ __forceinline__ float bflo(unsigned u) { return __builtin_bit_cast(float, u << 16); }
__device__ __forceinline__ float bfhi(unsigned u) { return __builtin_bit_cast(float, u & 0xffff0000u); }

// ---- fp8 e4m3 pack/unpack (HW cvt on gfx950; software fallback) ----
__device__ __forceinline__ unsigned char f2fp8_sw(float f) {
    unsigned u = __builtin_bit_cast(unsigned, f);
    unsigned s = (u >> 24) & 0x80;
    unsigned a = u & 0x7fffffffu;
    if (a < 0x3c800000u) return (unsigned char)s;          // |x| < 2^-6 -> +-0 (flush)
    if (a > 0x43e00000u) a = 0x43e00000u;                  // clamp to 448
    unsigned lsb = (a >> 20) & 1;
    a += 0x7ffffu + lsb;                                   // RNE to 3 mantissa bits
    unsigned e = (a >> 23) - 120;                          // e4m3 bias 7
    unsigned m = (a >> 20) & 7;
    return (unsigned char)(s | (e << 3) | m);
}
__device__ __forceinline__ float fp82f_sw(unsigned b) {
    unsigned s = (b & 0x80u) << 24;
    unsigned e = (b >> 3) & 15, m = b & 7;
    if (e == 0) {
        float v = (float)m * 0.001953125f;                 // m * 2^-9
        return (b & 0x80u) ? -v : v;
    }
    return __builtin_bit_cast(float, s | ((e + 120) << 23) | (m << 20));
}
__device__ __forceinline__ unsigned short pk_fp8(float a, float b) {
#if __has_builtin(__builtin_amdgcn_cvt_pk_fp8_f32)
    return (unsigned short)__builtin_amdgcn_cvt_pk_fp8_f32(a, b, 0u, false);
#else
    return (unsigned short)(f2fp8_sw(a) | ((unsigned)f2fp8_sw(b) << 8));
#endif
}
__device__ __forceinline__ f32x2 unpk_fp8(unsigned short v) {
#if __has_builtin(__builtin_amdgcn_cvt_pk_f32_fp8)
    return __builtin_amdgcn_cvt_pk_f32_fp8((unsigned)v, false);
#else
    f32x2 r; r[0] = fp82f_sw(v & 0xffu); r[1] = fp82f_sw(v >> 8); return r;
#endif
}

// ---------------- K0: pack [W1s;W1n] -> bf16 frags | fold W2*@Wf ----------------
__global__ __launch_bounds__(256) void k_init(const float* __restrict__ W1s,
                                              const float* __restrict__ W1n,
                                              const float* __restrict__ W2s,
                                              const float* __restrict__ W2n,
                                              const float* __restrict__ b2,
                                              const float* __restrict__ Wf,
                                              const float* __restrict__ bf,
                                              unsigned short* __restrict__ wpack,
                                              float* __restrict__ wc) {
    int blk = blockIdx.x;
    int tid = threadIdx.x;
    if (blk < NB_PACK) {
        // wpack[((nt*8+ks)*64+ln)*8 + j] = Wcat[ks*32+(ln>>4)*8+j][nt*16+(ln&15)]
        int idx = blk * 256 + tid;   // 32768 total
        int j = idx & 7;
        int ln = (idx >> 3) & 63;
        int ks = (idx >> 9) & 7;
        int nt = idx >> 12;
        int krow = ks * 32 + ((ln >> 4) << 3) + j;
        int col = nt * 16 + (ln & 15);
        float v = (krow < 128) ? W1s[krow * 128 + col] : W1n[(krow - 128) * 128 + col];
        wpack[idx] = f2bf(v);
    } else {
        // wc[0..255]=Wcs[k][c], [256..511]=Wcn[k][c], [512..513]=bc
        int role = blk - NB_PACK;   // 0: Wcs, 1: Wcn + bc
        int k = tid >> 1, c = tid & 1;
        const float* W = role == 0 ? W2s : W2n;
        float s = 0.f;
        for (int j = 0; j < 128; ++j) s += W[k * 128 + j] * Wf[j * 2 + c];
        wc[role * 256 + k * 2 + c] = s;
        if (role == 1 && tid < 2) {
            float sb = bf[tid];
            for (int j = 0; j < 128; ++j) sb += b2[j] * Wf[j * 2 + tid];
            wc[512 + tid] = sb;
        }
    }
}

// ---------------- K1: {edge partition} || {z,y GEMM} interleaved even/odd ----------------
__global__ __launch_bounds__(512) void k_pg(const float* __restrict__ x,
                                            const int* __restrict__ src,
                                            const int* __restrict__ dst,
                                            const unsigned short* __restrict__ wpack,
                                            const float* __restrict__ b1,
                                            unsigned* __restrict__ seg,
                                            int* __restrict__ segcnt,
                                            unsigned short* __restrict__ zb,
                                            unsigned char* __restrict__ yb8) {
    __shared__ int hist[NBIN];
    int blk = blockIdx.x;
    int tid = threadIdx.x;

    if ((blk & 1) == 0) {
        // ---- partition task g: 2048 edges read ONCE, binned by dst>>9 ----
        int g = blk >> 1;
        for (int i = tid; i < NBIN; i += 512) hist[i] = 0;
        __syncthreads();
        int e0 = g * CHUNK_A + tid * 4;
        bool v = e0 < N_EDGES;                    // N_EDGES % 4 == 0: all-or-nothing
        i32x4 d4 = {0,0,0,0}, s4 = d4;
        if (v) {
            d4 = *(const i32x4*)(dst + e0);
            s4 = *(const i32x4*)(src + e0);
        }
#pragma unroll
        for (int j = 0; j < 4; ++j) {
            if (v) {
                int b = (int)((unsigned)d4[j] >> 9);
                int lpos = atomicAdd(&hist[b], 1);
                if (lpos < NSLOT)
                    seg[((size_t)b * N_PARTS + g) * NSLOT + lpos] =
                        ((unsigned)d4[j] << 16) | (unsigned)s4[j];
            }
        }
        __syncthreads();
        for (int i = tid; i < NBIN; i += 512) {
            int h = hist[i];
            segcnt[i * N_PARTS + g] = h < NSLOT ? h : NSLOT;
        }
    } else {
        // ---- dense GEMM: 128-row tile, z = x@W1s+b1 (bf16), y = x@W1n (fp8) ----
        int g4 = blk >> 1;                         // 0..390 == NB_GEMM-1
        int wavein = tid >> 6;
        int lane = tid & 63;
        int l15 = lane & 15;
        int rowBase = g4 * 128 + wavein * 16;
        int arow = rowBase + l15;
        if (arow >= N_NODES) arow = N_NODES - 1;   // tail clamp; stores guarded
        int koff = (lane >> 4) << 3;

        const float* xrow = x + (size_t)arow * 128 + koff;   // x is L3-resident
        bf16x8 a[4];
#pragma unroll
        for (int ks = 0; ks < 4; ++ks) {
            f32x4 f0 = *(const f32x4*)(xrow + ks * 32);
            f32x4 f1 = *(const f32x4*)(xrow + ks * 32 + 4);
            bf16x8 t;
            t[0] = (short)f2bf(f0[0]); t[1] = (short)f2bf(f0[1]);
            t[2] = (short)f2bf(f0[2]); t[3] = (short)f2bf(f0[3]);
            t[4] = (short)f2bf(f1[0]); t[5] = (short)f2bf(f1[1]);
            t[6] = (short)f2bf(f1[2]); t[7] = (short)f2bf(f1[3]);
            a[ks] = t;
        }

        f32x4 zacc[8] = {};
        f32x4 yacc[8] = {};
        const bf16x8* wp = (const bf16x8*)wpack + lane;      // 64 KB, L2-broadcast
        __builtin_amdgcn_s_setprio(1);
#pragma unroll
        for (int nt = 0; nt < 8; ++nt) {
#pragma unroll
            for (int ks = 0; ks < 4; ++ks)
                zacc[nt] = __builtin_amdgcn_mfma_f32_16x16x32_bf16(a[ks], wp[(nt * 8 + ks) * 64], zacc[nt], 0, 0, 0);
#pragma unroll
            for (int ks = 0; ks < 4; ++ks)
                yacc[nt] = __builtin_amdgcn_mfma_f32_16x16x32_bf16(a[ks], wp[(nt * 8 + 4 + ks) * 64], yacc[nt], 0, 0, 0);
        }
        __builtin_amdgcn_s_setprio(0);

        // C/D layout: col = lane&15, row = (lane>>4)*4 + reg
        // paired-column store: pair p2 = k*16+l15 -> cols (32k+l15, 32k+16+l15)
        int crow0 = rowBase + ((lane >> 4) << 2);
#pragma unroll
        for (int k = 0; k < 4; ++k) {
            int colA = k * 32 + l15;
            float biasA = b1[colA];
            float biasB = b1[colA + 16];
            int p2 = k * 16 + l15;
#pragma unroll
            for (int r = 0; r < 4; ++r) {
                int row = crow0 + r;
                if (row < N_NODES) {
                    unsigned zu = (unsigned)f2bf(zacc[2 * k][r] + biasA) |
                                  ((unsigned)f2bf(zacc[2 * k + 1][r] + biasB) << 16);
                    *(unsigned*)(zb + (size_t)row * 128 + 2 * p2) = zu;
                    *(unsigned short*)(yb8 + (size_t)row * 128 + 2 * p2) =
                        pk_fp8(yacc[2 * k][r], yacc[2 * k + 1][r]);
                }
            }
        }
    }
}

// ---------------- K2: atomic-free bin build (one wide block per bin) ----------------
__global__ __launch_bounds__(512) void k_build(const unsigned* __restrict__ seg,
                                               const int* __restrict__ segcnt,
                                               int* __restrict__ cnt,
                                               unsigned short* __restrict__ bucket) {
    int b = blockIdx.x;                  // blk == bin -> blk%8 == bin%8 (L2 homing)
    int tid = threadIdx.x;
    __shared__ int cur[BIN_SZ];
    __shared__ int scnt[N_PARTS];
    for (int i = tid; i < BIN_SZ; i += 512) cur[i] = 0;
    for (int i = tid; i < N_PARTS; i += 512) scnt[i] = segcnt[b * N_PARTS + i];
    __syncthreads();
    int wave = tid >> 6, lane = tid & 63;
    const unsigned* segb = seg + (size_t)b * N_PARTS * NSLOT;
    // wave w owns parts w, w+8, ... (49 parts); batches of 4 -> 13 latency steps
    for (int j = 0; j < 13; ++j) {
        unsigned v[4];
#pragma unroll
        for (int t = 0; t < 4; ++t) {
            int p = wave + 8 * (j * 4 + t);
            int n = p < N_PARTS ? scnt[p] : 0;
            v[t] = lane < n ? segb[(size_t)p * NSLOT + lane] : 0xffffffffu;
        }
#pragma unroll
        for (int t = 0; t < 4; ++t) {
            if (v[t] != 0xffffffffu) {
                int d = (int)(v[t] >> 16);
                int p = atomicAdd(&cur[d & (BIN_SZ - 1)], 1);
                if (p < CAP) bucket[(size_t)d * CAP + p] = (unsigned short)(v[t] & 0xffffu);
            }
        }
    }
    __syncthreads();
    for (int i = tid; i < BIN_SZ; i += 512) {
        int node = (b << 9) + i;
        if (node < N_NODES) cnt[node] = cur[i];
    }
}

// ---------------- K3: h1 = relu(z + mean_neigh(y)); pq = {h1@Wcs, h1@Wcn} ----------------
__global__ __launch_bounds__(256) void k_agg2(const unsigned char* __restrict__ yb8,
                                              const unsigned short* __restrict__ zb,
                                              const int* __restrict__ cnt,
                                              const unsigned short* __restrict__ bucket,
                                              const float* __restrict__ wc,
                                              float* __restrict__ pq) {
    int blk = blockIdx.x;
    int wavein = threadIdx.x >> 6;
    int lane = threadIdx.x & 63;
    int xcd = blk & 7;
    int i = (blk >> 3) * 4 + wavein;            // node-in-xcd
    int b = xcd + ((i >> 9) << 3);              // bin; bin%8==xcd matches build homing
    if (b >= NBIN) return;
    int node = (b << 9) + (i & 511);
    if (node >= N_NODES) return;

    int deg = cnt[node];
    int colA = ((lane >> 4) << 5) + (lane & 15);
    int colB = colA + 16;
    unsigned zu = *(const unsigned*)(zb + (size_t)node * 128 + 2 * lane);
    float2 wsA = *(const float2*)(wc + 2 * colA);
    float2 wsB = *(const float2*)(wc + 2 * colB);
    float2 wnA = *(const float2*)(wc + 256 + 2 * colA);
    float2 wnB = *(const float2*)(wc + 256 + 2 * colB);

    int n = deg < CAP ? deg : CAP;
    const unsigned short* bk = bucket + (size_t)node * CAP;
    const unsigned char* ybl = yb8 + 2 * lane;
    float ax0 = 0.f, ay0 = 0.f, ax1 = 0.f, ay1 = 0.f;
    float ax2 = 0.f, ay2 = 0.f, ax3 = 0.f, ay3 = 0.f;
    int e = 0;
    for (; e + 16 <= n; e += 16) {
        uint4 ia = *(const uint4*)(bk + e);       // 8 packed ushort indices
        uint4 ib = *(const uint4*)(bk + e + 8);
        int s0  = ia.x & 0xffff, s1  = ia.x >> 16, s2  = ia.y & 0xffff, s3  = ia.y >> 16;
        int s4  = ia.z & 0xffff, s5  = ia.z >> 16, s6  = ia.w & 0xffff, s7  = ia.w >> 16;
        int s8  = ib.x & 0xffff, s9  = ib.x >> 16, s10 = ib.y & 0xffff, s11 = ib.y >> 16;
        int s12 = ib.z & 0xffff, s13 = ib.z >> 16, s14 = ib.w & 0xffff, s15 = ib.w >> 16;
        unsigned short t0  = *(const unsigned short*)(ybl + (size_t)s0  * 128);
        unsigned short t1  = *(const unsigned short*)(ybl + (size_t)s1  * 128);
        unsigned short t2  = *(const unsigned short*)(ybl + (size_t)s2  * 128);
        unsigned short t3  = *(const unsigned short*)(ybl + (size_t)s3  * 128);
        unsigned short t4  = *(const unsigned short*)(ybl + (size_t)s4  * 128);
        unsigned short t5  = *(const unsigned short*)(ybl + (size_t)s5  * 128);
        unsigned short t6  = *(const unsigned short*)(ybl + (size_t)s6  * 128);
        unsigned short t7  = *(const unsigned short*)(ybl + (size_t)s7  * 128);
        unsigned short t8  = *(const unsigned short*)(ybl + (size_t)s8  * 128);
        unsigned short t9  = *(const unsigned short*)(ybl + (size_t)s9  * 128);
        unsigned short t10 = *(const unsigned short*)(ybl + (size_t)s10 * 128);
        unsigned short t11 = *(const unsigned short*)(ybl + (size_t)s11 * 128);
        unsigned short t12 = *(const unsigned short*)(ybl + (size_t)s12 * 128);
        unsigned short t13 = *(const unsigned short*)(ybl + (size_t)s13 * 128);
        unsigned short t14 = *(const unsigned short*)(ybl + (size_t)s14 * 128);
        unsigned short t15 = *(const unsigned short*)(ybl + (size_t)s15 * 128);
        f32x2 v0 = unpk_fp8(t0),  v1 = unpk_fp8(t1),  v2 = unpk_fp8(t2),  v3 = unpk_fp8(t3);
        f32x2 v4 = unpk_fp8(t4),  v5 = unpk_fp8(t5),  v6 = unpk_fp8(t6),  v7 = unpk_fp8(t7);
        f32x2 v8 = unpk_fp8(t8),  v9 = unpk_fp8(t9),  v10 = unpk_fp8(t10), v11 = unpk_fp8(t11);
        f32x2 v12 = unpk_fp8(t12), v13 = unpk_fp8(t13), v14 = unpk_fp8(t14), v15 = unpk_fp8(t15);
        ax0 += v0[0];  ay0 += v0[1];  ax1 += v1[0];  ay1 += v1[1];
        ax2 += v2[0];  ay2 += v2[1];  ax3 += v3[0];  ay3 += v3[1];
        ax0 += v4[0];  ay0 += v4[1];  ax1 += v5[0];  ay1 += v5[1];
        ax2 += v6[0];  ay2 += v6[1];  ax3 += v7[0];  ay3 += v7[1];
        ax0 += v8[0];  ay0 += v8[1];  ax1 += v9[0];  ay1 += v9[1];
        ax2 += v10[0]; ay2 += v10[1]; ax3 += v11[0]; ay3 += v11[1];
        ax0 += v12[0]; ay0 += v12[1]; ax1 += v13[0]; ay1 += v13[1];
        ax2 += v14[0]; ay2 += v14[1]; ax3 += v15[0]; ay3 += v15[1];
    }
    if (e + 8 <= n) {
        uint4 ia = *(const uint4*)(bk + e);
        int s0 = ia.x & 0xffff, s1 = ia.x >> 16, s2 = ia.y & 0xffff, s3 = ia.y >> 16;
        int s4 = ia.z & 0xffff, s5 = ia.z >> 16, s6 = ia.w & 0xffff, s7 = ia.w >> 16;
        unsigned short t0 = *(const unsigned short*)(ybl + (size_t)s0 * 128);
        unsigned short t1 = *(const unsigned short*)(ybl + (size_t)s1 * 128);
        unsigned short t2 = *(const unsigned short*)(ybl + (size_t)s2 * 128);
        unsigned short t3 = *(const unsigned short*)(ybl + (size_t)s3 * 128);
        unsigned short t4 = *(const unsigned short*)(ybl + (size_t)s4 * 128);
        unsigned short t5 = *(const unsigned short*)(ybl + (size_t)s5 * 128);
        unsigned short t6 = *(const unsigned short*)(ybl + (size_t)s6 * 128);
        unsigned short t7 = *(const unsigned short*)(ybl + (size_t)s7 * 128);
        f32x2 v0 = unpk_fp8(t0), v1 = unpk_fp8(t1), v2 = unpk_fp8(t2), v3 = unpk_fp8(t3);
        f32x2 v4 = unpk_fp8(t4), v5 = unpk_fp8(t5), v6 = unpk_fp8(t6), v7 = unpk_fp8(t7);
        ax0 += v0[0]; ay0 += v0[1]; ax1 += v1[0]; ay1 += v1[1];
        ax2 += v2[0]; ay2 += v2[1]; ax3 += v3[0]; ay3 += v3[1];
        ax0 += v4[0]; ay0 += v4[1]; ax1 += v5[0]; ay1 += v5[1];
        ax2 += v6[0]; ay2 += v6[1]; ax3 += v7[0]; ay3 += v7[1];
        e += 8;
    }
    if (e + 4 <= n) {
        uint2 ia = *(const uint2*)(bk + e);
        int s0 = ia.x & 0xffff, s1 = ia.x >> 16, s2 = ia.y & 0xffff, s3 = ia.y >> 16;
        unsigned short t0 = *(const unsigned short*)(ybl + (size_t)s0 * 128);
        unsigned short t1 = *(const unsigned short*)(ybl + (size_t)s1 * 128);
        unsigned short t2 = *(const unsigned short*)(ybl + (size_t)s2 * 128);
        unsigned short t3 = *(const unsigned short*)(ybl + (size_t)s3 * 128);
        f32x2 v0 = unpk_fp8(t0), v1 = unpk_fp8(t1), v2 = unpk_fp8(t2), v3 = unpk_fp8(t3);
        ax0 += v0[0]; ay0 += v0[1]; ax1 += v1[0]; ay1 += v1[1];
        ax2 += v2[0]; ay2 += v2[1]; ax3 += v3[0]; ay3 += v3[1];
        e += 4;
    }
    for (; e < n; ++e) {
        unsigned short t = *(const unsigned short*)(ybl + (size_t)bk[e] * 128);
        f32x2 v = unpk_fp8(t);
        ax0 += v[0]; ay0 += v[1];
    }
    float inv = 1.0f / fmaxf((float)deg, 1.0f);
    float mx = ((ax0 + ax1) + (ax2 + ax3)) * inv;
    float my = ((ay0 + ay1) + (ay2 + ay3)) * inv;

    float h0 = fmaxf(bflo(zu) + mx, 0.f);       // col colA
    float h1v = fmaxf(bfhi(zu) + my, 0.f);      // col colB

    float p0 = h0 * wsA.x + h1v * wsB.x;
    float p1 = h0 * wsA.y + h1v * wsB.y;
    float q0 = h0 * wnA.x + h1v * wnB.x;
    float q1 = h0 * wnA.y + h1v * wnB.y;
#pragma unroll
    for (int off = 32; off >= 1; off >>= 1) {
        p0 += __shfl_xor(p0, off, 64);
        p1 += __shfl_xor(p1, off, 64);
        q0 += __shfl_xor(q0, off, 64);
        q1 += __shfl_xor(q1, off, 64);
    }
    if (lane == 0) {
        float4 o; o.x = p0; o.y = p1; o.z = q0; o.w = q1;
        ((float4*)pq)[node] = o;
    }
}

// ---------------- K4: out[n] = pq[n].p + mean_src(pq[src].q) + bc ----------------
__global__ __launch_bounds__(256) void k_final(const float* __restrict__ pq,
                                               const int* __restrict__ cnt,
                                               const unsigned short* __restrict__ bucket,
                                               const float* __restrict__ wc,
                                               float* __restrict__ out) {
    int blk = blockIdx.x;
    int wavein = threadIdx.x >> 6;
    int lane = threadIdx.x & 63;
    int xcd = blk & 7;
    int i = (blk >> 3) * 4 + wavein;
    int b = xcd + ((i >> 9) << 3);
    if (b >= NBIN) return;
    int node = (b << 9) + (i & 511);
    if (node >= N_NODES) return;

    int deg = cnt[node];
    int n = deg < CAP ? deg : CAP;
    float qx = 0.f, qy = 0.f;
    if (lane < n) {
        int s = bucket[(size_t)node * CAP + lane];
        float2 q = *(const float2*)(pq + (size_t)s * 4 + 2);
        qx = q.x; qy = q.y;
    }
#pragma unroll
    for (int off = 32; off >= 1; off >>= 1) {
        qx += __shfl_xor(qx, off, 64);
        qy += __shfl_xor(qy, off, 64);
    }
    if (lane == 0) {
        float inv = 1.0f / fmaxf((float)deg, 1.0f);
        float2 p = *(const float2*)(pq + (size_t)node * 4);
        out[(size_t)node * 2 + 0] = p.x + qx * inv + wc[512];
        out[(size_t)node * 2 + 1] = p.y + qy * inv + wc[513];
    }
}

extern "C" void kernel_launch(void* const* d_in, const int* in_sizes, int n_in,
                              void* d_out, int out_size, void* d_ws, size_t ws_size,
                              hipStream_t stream) {
    const float* x   = (const float*)d_in[0];
    const int* esrc  = (const int*)d_in[1];
    const int* edst  = (const int*)d_in[2];
    const float* W1s = (const float*)d_in[3];
    const float* W1n = (const float*)d_in[4];
    const float* b1  = (const float*)d_in[5];
    const float* W2s = (const float*)d_in[6];
    const float* W2n = (const float*)d_in[7];
    const float* b2  = (const float*)d_in[8];
    const float* Wf  = (const float*)d_in[9];
    const float* bf  = (const float*)d_in[10];
    float* out = (float*)d_out;

    char* ws = (char*)d_ws;
    auto alloc = [&](size_t bytes) {
        char* p = ws;
        ws += (bytes + 255) & ~(size_t)255;
        return p;
    };
    int*            cnt    = (int*)           alloc((size_t)N_NODES * 4);
    unsigned short* bucket = (unsigned short*)alloc((size_t)N_NODES * CAP * 2);
    unsigned*       seg    = (unsigned*)      alloc((size_t)NBIN * N_PARTS * NSLOT * 4);
    int*            segcnt = (int*)           alloc((size_t)NBIN * N_PARTS * 4);
    unsigned short* zb     = (unsigned short*)alloc((size_t)N_NODES * 128 * 2);
    unsigned char*  yb8    = (unsigned char*) alloc((size_t)N_NODES * 128);
    unsigned short* wpack  = (unsigned short*)alloc(8 * 8 * 64 * 8 * 2);
    float*          pq     = (float*)         alloc((size_t)N_NODES * 4 * 4);
    float*          wc     = (float*)         alloc(1024 * 4);

    k_init<<<NB_INIT, 256, 0, stream>>>(W1s, W1n, W2s, W2n, b2, Wf, bf, wpack, wc);
    k_pg<<<NB_PG, 512, 0, stream>>>(x, esrc, edst, wpack, b1, seg, segcnt, zb, yb8);
    k_build<<<NB_BUILD, 512, 0, stream>>>(seg, segcnt, cnt, bucket);
    k_agg2<<<NB_AGG, 256, 0, stream>>>(yb8, zb, cnt, bucket, wc, pq);
    k_final<<<NB_AGG, 256, 0, stream>>>(pq, cnt, bucket, wc, out);
}

// Round 18
// 75.402 us; speedup vs baseline: 3.3657x; 1.3191x over previous
//
#include <hip/hip_runtime.h>
#include <cstdint>
#include <cstddef>

#define N_NODES 50000
#define N_EDGES 800000
#define CAP 64        // max in-degree; Poisson(16): P(>64) astronomically small

#define BIN_SZ 512                    // nodes per bin (pow2: bin = dst>>9)
#define NBIN 98                       // ceil(50000/512)
#define NSLOT 64                      // per-(bin,part) slot; Binom(2048,.0102) mean 21, +9.5 sigma

#define CHUNK_A 2048
#define N_PARTS 391                   // 391*2048 = 800768 >= 800000

// K0 (pre): partition | pack W | combine
#define NB_PART N_PARTS
#define NB_PACK 128
#define NB_COMB 2
#define NB_PRE  (NB_PART + NB_PACK + NB_COMB)

// K1 (main): 512-thread blocks, groups of 5 = 1 build (bin G) + 4 gemm (128 rows each)
#define NB_GEMM 391                   // ceil(50000/128)
#define NB_MAIN (NBIN * 5)            // 490; gemm slots 98*4=392 >= 391

// K2/K3: xcd = blk&7; i = (blk>>3)*4+wavein; b = xcd + 8*(i>>9); node = b*512 + (i&511)
#define NB_AGG 13312                  // 8 * 1664

typedef __attribute__((ext_vector_type(8))) short bf16x8;   // MFMA A/B frag (4 VGPRs)
typedef __attribute__((ext_vector_type(4))) float f32x4;    // MFMA C/D frag
typedef __attribute__((ext_vector_type(2))) float f32x2;
typedef __attribute__((ext_vector_type(4))) int   i32x4;

__device__ __forceinline__ unsigned short f2bf(float f) {
    unsigned u = __builtin_bit_cast(unsigned, f);
    u += 0x7fff + ((u >> 16) & 1);          // round-to-nearest-even
    return (unsigned short)(u >> 16);
}
__device__ __forceinline__ float bflo(unsigned u) { return __builtin_bit_cast(float, u << 16); }
__device__ __forceinline__ float bfhi(unsigned u) { return __builtin_bit_cast(float, u & 0xffff0000u); }

// ---- fp8 e4m3 pack/unpack (HW cvt on gfx950; software fallback) ----
__device__ __forceinline__ unsigned char f2fp8_sw(float f) {
    unsigned u = __builtin_bit_cast(unsigned, f);
    unsigned s = (u >> 24) & 0x80;
    unsigned a = u & 0x7fffffffu;
    if (a < 0x3c800000u) return (unsigned char)s;          // |x| < 2^-6 -> +-0 (flush)
    if (a > 0x43e00000u) a = 0x43e00000u;                  // clamp to 448
    unsigned lsb = (a >> 20) & 1;
    a += 0x7ffffu + lsb;                                   // RNE to 3 mantissa bits
    unsigned e = (a >> 23) - 120;                          // e4m3 bias 7
    unsigned m = (a >> 20) & 7;
    return (unsigned char)(s | (e << 3) | m);
}
__device__ __forceinline__ float fp82f_sw(unsigned b) {
    unsigned s = (b & 0x80u) << 24;
    unsigned e = (b >> 3) & 15, m = b & 7;
    if (e == 0) {
        float v = (float)m * 0.001953125f;                 // m * 2^-9
        return (b & 0x80u) ? -v : v;
    }
    return __builtin_bit_cast(float, s | ((e + 120) << 23) | (m << 20));
}
__device__ __forceinline__ unsigned short pk_fp8(float a, float b) {
#if __has_builtin(__builtin_amdgcn_cvt_pk_fp8_f32)
    return (unsigned short)__builtin_amdgcn_cvt_pk_fp8_f32(a, b, 0u, false);
#else
    return (unsigned short)(f2fp8_sw(a) | ((unsigned)f2fp8_sw(b) << 8));
#endif
}
__device__ __forceinline__ f32x2 unpk_fp8(unsigned short v) {
#if __has_builtin(__builtin_amdgcn_cvt_pk_f32_fp8)
    return __builtin_amdgcn_cvt_pk_f32_fp8((unsigned)v, false);
#else
    f32x2 r; r[0] = fp82f_sw(v & 0xffu); r[1] = fp82f_sw(v >> 8); return r;
#endif
}

// ---------------- K0: LDS-staged partition | pack W | fold W2*@Wf ----------------
__global__ __launch_bounds__(256) void k_pre(const int* __restrict__ src,
                                             const int* __restrict__ dst,
                                             const float* __restrict__ W1s,
                                             const float* __restrict__ W1n,
                                             const float* __restrict__ W2s,
                                             const float* __restrict__ W2n,
                                             const float* __restrict__ b2,
                                             const float* __restrict__ Wf,
                                             const float* __restrict__ bf,
                                             unsigned* __restrict__ seg,
                                             int* __restrict__ segcnt,
                                             unsigned short* __restrict__ wpack,
                                             float* __restrict__ wc) {
    int blk = blockIdx.x;
    int tid = threadIdx.x;

    if (blk < NB_PART) {
        // ---- partition: 2048 edges read ONCE, staged in LDS, written coalesced ----
        __shared__ int hist[NBIN];
        __shared__ unsigned data[NBIN * NSLOT];   // 25 KB
        for (int i = tid; i < NBIN; i += 256) hist[i] = 0;
        __syncthreads();
        int g = blk;
        int e0 = g * CHUNK_A + tid * 8;
        bool v = e0 < N_EDGES;                    // N_EDGES % 8 == 0: all-or-nothing
        i32x4 da = {0,0,0,0}, db = da, sa = da, sb = da;
        if (v) {
            da = *(const i32x4*)(dst + e0);
            db = *(const i32x4*)(dst + e0 + 4);
            sa = *(const i32x4*)(src + e0);
            sb = *(const i32x4*)(src + e0 + 4);
        }
        int d[8], s[8];
#pragma unroll
        for (int j = 0; j < 4; ++j) { d[j] = da[j]; s[j] = sa[j]; d[4 + j] = db[j]; s[4 + j] = sb[j]; }
#pragma unroll
        for (int j = 0; j < 8; ++j) {
            if (v) {
                int b = (int)((unsigned)d[j] >> 9);
                int lpos = atomicAdd(&hist[b], 1);
                if (lpos < NSLOT)
                    data[b * NSLOT + lpos] = ((unsigned)d[j] << 16) | (unsigned)s[j];
            }
        }
        __syncthreads();
        // coalesced write-out: wave w handles bins w, w+4, ...; lanes 0..cnt-1 store run
        int wave = tid >> 6, lane = tid & 63;
        for (int b = wave; b < NBIN; b += 4) {
            int h = hist[b];
            int n = h < NSLOT ? h : NSLOT;
            if (lane < n)
                seg[((size_t)b * N_PARTS + g) * NSLOT + lane] = data[b * NSLOT + lane];
            if (lane == 0) segcnt[b * N_PARTS + g] = n;
        }
    } else if (blk < NB_PART + NB_PACK) {
        // wpack[((nt*8+ks)*64+ln)*8 + j] = Wcat[ks*32+(ln>>4)*8+j][nt*16+(ln&15)]
        int idx = (blk - NB_PART) * 256 + tid;   // 32768 total
        int j = idx & 7;
        int ln = (idx >> 3) & 63;
        int ks = (idx >> 9) & 7;
        int nt = idx >> 12;
        int krow = ks * 32 + ((ln >> 4) << 3) + j;
        int col = nt * 16 + (ln & 15);
        float v = (krow < 128) ? W1s[krow * 128 + col] : W1n[(krow - 128) * 128 + col];
        wpack[idx] = f2bf(v);
    } else {
        // wc[0..255]=Wcs[k][c], [256..511]=Wcn[k][c], [512..513]=bc
        int role = blk - NB_PART - NB_PACK;   // 0: Wcs, 1: Wcn + bc
        int k = tid >> 1, c = tid & 1;
        const float* W = role == 0 ? W2s : W2n;
        float s = 0.f;
        for (int j = 0; j < 128; ++j) s += W[k * 128 + j] * Wf[j * 2 + c];
        wc[role * 256 + k * 2 + c] = s;
        if (role == 1 && tid < 2) {
            float sb = bf[tid];
            for (int j = 0; j < 128; ++j) sb += b2[j] * Wf[j * 2 + tid];
            wc[512 + tid] = sb;
        }
    }
}

// ---------------- K1: interleaved {wide atomic-free bin build} || {z,y GEMM, 128 rows} ----------------
// paired-column layout: pair p = k*16 + (lane&15) holds cols (32k + l15, 32k + 16 + l15)
__global__ __launch_bounds__(512) void k_main(const float* __restrict__ x,
                                              const unsigned* __restrict__ seg,
                                              const int* __restrict__ segcnt,
                                              const unsigned short* __restrict__ wpack,
                                              const float* __restrict__ b1,
                                              int* __restrict__ cnt,
                                              unsigned short* __restrict__ bucket,
                                              unsigned short* __restrict__ zb,
                                              unsigned char* __restrict__ yb8) {
    int blk = blockIdx.x;
    int tid = threadIdx.x;
    int G = blk / 5;
    int pos = blk - G * 5;

    if (pos == 0) {
        // ---- build bin G: 8 waves, LDS cursors, batch-4 loads in flight ----
        int b = G;
        __shared__ int cur[BIN_SZ];
        __shared__ int scnt[N_PARTS];
        for (int i = tid; i < BIN_SZ; i += 512) cur[i] = 0;
        for (int i = tid; i < N_PARTS; i += 512) scnt[i] = segcnt[b * N_PARTS + i];
        __syncthreads();
        int wave = tid >> 6, lane = tid & 63;
        const unsigned* segb = seg + (size_t)b * N_PARTS * NSLOT;
        for (int j = 0; j < 13; ++j) {
            unsigned v[4];
#pragma unroll
            for (int t = 0; t < 4; ++t) {
                int p = wave + 8 * (j * 4 + t);
                int n = p < N_PARTS ? scnt[p] : 0;
                v[t] = lane < n ? segb[(size_t)p * NSLOT + lane] : 0xffffffffu;
            }
#pragma unroll
            for (int t = 0; t < 4; ++t) {
                if (v[t] != 0xffffffffu) {
                    int d = (int)(v[t] >> 16);
                    int p = atomicAdd(&cur[d & (BIN_SZ - 1)], 1);
                    if (p < CAP) bucket[(size_t)d * CAP + p] = (unsigned short)(v[t] & 0xffffu);
                }
            }
        }
        __syncthreads();
        for (int i = tid; i < BIN_SZ; i += 512) {
            int node = (b << 9) + i;
            if (node < N_NODES) cnt[node] = cur[i];
        }
    } else {
        // ---- dense GEMM: 128-row tile (8 waves x 16 rows), z = x@W1s+b1 and y = x@W1n ----
        int g4 = G * 4 + (pos - 1);
        if (g4 >= NB_GEMM) return;
        int wid = tid >> 6;
        int lane = tid & 63;
        int l15 = lane & 15;
        int rowBase = g4 * 128 + wid * 16;
        int arow = rowBase + l15;
        if (arow >= N_NODES) arow = N_NODES - 1;   // tail clamp; stores guarded
        int koff = (lane >> 4) << 3;

        const float* xrow = x + (size_t)arow * 128 + koff;   // x is L3-resident
        bf16x8 a[4];
#pragma unroll
        for (int ks = 0; ks < 4; ++ks) {
            f32x4 f0 = *(const f32x4*)(xrow + ks * 32);
            f32x4 f1 = *(const f32x4*)(xrow + ks * 32 + 4);
            bf16x8 t;
            t[0] = (short)f2bf(f0[0]); t[1] = (short)f2bf(f0[1]);
            t[2] = (short)f2bf(f0[2]); t[3] = (short)f2bf(f0[3]);
            t[4] = (short)f2bf(f1[0]); t[5] = (short)f2bf(f1[1]);
            t[6] = (short)f2bf(f1[2]); t[7] = (short)f2bf(f1[3]);
            a[ks] = t;
        }

        f32x4 zacc[8] = {};
        f32x4 yacc[8] = {};
        const bf16x8* wp = (const bf16x8*)wpack + lane;
        __builtin_amdgcn_s_setprio(1);
#pragma unroll
        for (int nt = 0; nt < 8; ++nt) {
#pragma unroll
            for (int ks = 0; ks < 4; ++ks)
                zacc[nt] = __builtin_amdgcn_mfma_f32_16x16x32_bf16(a[ks], wp[(nt * 8 + ks) * 64], zacc[nt], 0, 0, 0);
#pragma unroll
            for (int ks = 0; ks < 4; ++ks)
                yacc[nt] = __builtin_amdgcn_mfma_f32_16x16x32_bf16(a[ks], wp[(nt * 8 + 4 + ks) * 64], yacc[nt], 0, 0, 0);
        }
        __builtin_amdgcn_s_setprio(0);

        // C/D layout: col = lane&15, row = (lane>>4)*4 + reg
        // store pair p2 = k*16+l15 -> cols (32k+l15, 32k+16+l15)
        int crow0 = rowBase + ((lane >> 4) << 2);
#pragma unroll
        for (int k = 0; k < 4; ++k) {
            int colA = k * 32 + l15;
            float biasA = b1[colA];
            float biasB = b1[colA + 16];
            int p2 = k * 16 + l15;
#pragma unroll
            for (int r = 0; r < 4; ++r) {
                int row = crow0 + r;
                if (row < N_NODES) {
                    unsigned zu = (unsigned)f2bf(zacc[2 * k][r] + biasA) |
                                  ((unsigned)f2bf(zacc[2 * k + 1][r] + biasB) << 16);
                    *(unsigned*)(zb + (size_t)row * 128 + 2 * p2) = zu;
                    *(unsigned short*)(yb8 + (size_t)row * 128 + 2 * p2) =
                        pk_fp8(yacc[2 * k][r], yacc[2 * k + 1][r]);
                }
            }
        }
    }
}

// ---------------- K2: h1 = relu(z + mean_neigh(y)); pq = {h1@Wcs, h1@Wcn} ----------------
__global__ __launch_bounds__(256) void k_agg2(const unsigned char* __restrict__ yb8,
                                              const unsigned short* __restrict__ zb,
                                              const int* __restrict__ cnt,
                                              const unsigned short* __restrict__ bucket,
                                              const float* __restrict__ wc,
                                              float* __restrict__ pq) {
    int blk = blockIdx.x;
    int wavein = threadIdx.x >> 6;
    int lane = threadIdx.x & 63;
    int xcd = blk & 7;
    int i = (blk >> 3) * 4 + wavein;            // node-in-xcd
    int b = xcd + ((i >> 9) << 3);              // bin; bin%8==xcd matches build homing
    if (b >= NBIN) return;
    int node = (b << 9) + (i & 511);
    if (node >= N_NODES) return;

    int deg = cnt[node];
    int colA = ((lane >> 4) << 5) + (lane & 15);
    int colB = colA + 16;
    unsigned zu = *(const unsigned*)(zb + (size_t)node * 128 + 2 * lane);
    float2 wsA = *(const float2*)(wc + 2 * colA);
    float2 wsB = *(const float2*)(wc + 2 * colB);
    float2 wnA = *(const float2*)(wc + 256 + 2 * colA);
    float2 wnB = *(const float2*)(wc + 256 + 2 * colB);

    int n = deg < CAP ? deg : CAP;
    const unsigned short* bk = bucket + (size_t)node * CAP;
    const unsigned char* ybl = yb8 + 2 * lane;
    float ax0 = 0.f, ay0 = 0.f, ax1 = 0.f, ay1 = 0.f;
    float ax2 = 0.f, ay2 = 0.f, ax3 = 0.f, ay3 = 0.f;
    int e = 0;
    for (; e + 16 <= n; e += 16) {
        uint4 ia = *(const uint4*)(bk + e);       // 8 packed ushort indices
        uint4 ib = *(const uint4*)(bk + e + 8);
        int s0  = ia.x & 0xffff, s1  = ia.x >> 16, s2  = ia.y & 0xffff, s3  = ia.y >> 16;
        int s4  = ia.z & 0xffff, s5  = ia.z >> 16, s6  = ia.w & 0xffff, s7  = ia.w >> 16;
        int s8  = ib.x & 0xffff, s9  = ib.x >> 16, s10 = ib.y & 0xffff, s11 = ib.y >> 16;
        int s12 = ib.z & 0xffff, s13 = ib.z >> 16, s14 = ib.w & 0xffff, s15 = ib.w >> 16;
        unsigned short t0  = *(const unsigned short*)(ybl + (size_t)s0  * 128);
        unsigned short t1  = *(const unsigned short*)(ybl + (size_t)s1  * 128);
        unsigned short t2  = *(const unsigned short*)(ybl + (size_t)s2  * 128);
        unsigned short t3  = *(const unsigned short*)(ybl + (size_t)s3  * 128);
        unsigned short t4  = *(const unsigned short*)(ybl + (size_t)s4  * 128);
        unsigned short t5  = *(const unsigned short*)(ybl + (size_t)s5  * 128);
        unsigned short t6  = *(const unsigned short*)(ybl + (size_t)s6  * 128);
        unsigned short t7  = *(const unsigned short*)(ybl + (size_t)s7  * 128);
        unsigned short t8  = *(const unsigned short*)(ybl + (size_t)s8  * 128);
        unsigned short t9  = *(const unsigned short*)(ybl + (size_t)s9  * 128);
        unsigned short t10 = *(const unsigned short*)(ybl + (size_t)s10 * 128);
        unsigned short t11 = *(const unsigned short*)(ybl + (size_t)s11 * 128);
        unsigned short t12 = *(const unsigned short*)(ybl + (size_t)s12 * 128);
        unsigned short t13 = *(const unsigned short*)(ybl + (size_t)s13 * 128);
        unsigned short t14 = *(const unsigned short*)(ybl + (size_t)s14 * 128);
        unsigned short t15 = *(const unsigned short*)(ybl + (size_t)s15 * 128);
        f32x2 v0 = unpk_fp8(t0),  v1 = unpk_fp8(t1),  v2 = unpk_fp8(t2),  v3 = unpk_fp8(t3);
        f32x2 v4 = unpk_fp8(t4),  v5 = unpk_fp8(t5),  v6 = unpk_fp8(t6),  v7 = unpk_fp8(t7);
        f32x2 v8 = unpk_fp8(t8),  v9 = unpk_fp8(t9),  v10 = unpk_fp8(t10), v11 = unpk_fp8(t11);
        f32x2 v12 = unpk_fp8(t12), v13 = unpk_fp8(t13), v14 = unpk_fp8(t14), v15 = unpk_fp8(t15);
        ax0 += v0[0];  ay0 += v0[1];  ax1 += v1[0];  ay1 += v1[1];
        ax2 += v2[0];  ay2 += v2[1];  ax3 += v3[0];  ay3 += v3[1];
        ax0 += v4[0];  ay0 += v4[1];  ax1 += v5[0];  ay1 += v5[1];
        ax2 += v6[0];  ay2 += v6[1];  ax3 += v7[0];  ay3 += v7[1];
        ax0 += v8[0];  ay0 += v8[1];  ax1 += v9[0];  ay1 += v9[1];
        ax2 += v10[0]; ay2 += v10[1]; ax3 += v11[0]; ay3 += v11[1];
        ax0 += v12[0]; ay0 += v12[1]; ax1 += v13[0]; ay1 += v13[1];
        ax2 += v14[0]; ay2 += v14[1]; ax3 += v15[0]; ay3 += v15[1];
    }
    if (e + 8 <= n) {
        uint4 ia = *(const uint4*)(bk + e);
        int s0 = ia.x & 0xffff, s1 = ia.x >> 16, s2 = ia.y & 0xffff, s3 = ia.y >> 16;
        int s4 = ia.z & 0xffff, s5 = ia.z >> 16, s6 = ia.w & 0xffff, s7 = ia.w >> 16;
        unsigned short t0 = *(const unsigned short*)(ybl + (size_t)s0 * 128);
        unsigned short t1 = *(const unsigned short*)(ybl + (size_t)s1 * 128);
        unsigned short t2 = *(const unsigned short*)(ybl + (size_t)s2 * 128);
        unsigned short t3 = *(const unsigned short*)(ybl + (size_t)s3 * 128);
        unsigned short t4 = *(const unsigned short*)(ybl + (size_t)s4 * 128);
        unsigned short t5 = *(const unsigned short*)(ybl + (size_t)s5 * 128);
        unsigned short t6 = *(const unsigned short*)(ybl + (size_t)s6 * 128);
        unsigned short t7 = *(const unsigned short*)(ybl + (size_t)s7 * 128);
        f32x2 v0 = unpk_fp8(t0), v1 = unpk_fp8(t1), v2 = unpk_fp8(t2), v3 = unpk_fp8(t3);
        f32x2 v4 = unpk_fp8(t4), v5 = unpk_fp8(t5), v6 = unpk_fp8(t6), v7 = unpk_fp8(t7);
        ax0 += v0[0]; ay0 += v0[1]; ax1 += v1[0]; ay1 += v1[1];
        ax2 += v2[0]; ay2 += v2[1]; ax3 += v3[0]; ay3 += v3[1];
        ax0 += v4[0]; ay0 += v4[1]; ax1 += v5[0]; ay1 += v5[1];
        ax2 += v6[0]; ay2 += v6[1]; ax3 += v7[0]; ay3 += v7[1];
        e += 8;
    }
    if (e + 4 <= n) {
        uint2 ia = *(const uint2*)(bk + e);
        int s0 = ia.x & 0xffff, s1 = ia.x >> 16, s2 = ia.y & 0xffff, s3 = ia.y >> 16;
        unsigned short t0 = *(const unsigned short*)(ybl + (size_t)s0 * 128);
        unsigned short t1 = *(const unsigned short*)(ybl + (size_t)s1 * 128);
        unsigned short t2 = *(const unsigned short*)(ybl + (size_t)s2 * 128);
        unsigned short t3 = *(const unsigned short*)(ybl + (size_t)s3 * 128);
        f32x2 v0 = unpk_fp8(t0), v1 = unpk_fp8(t1), v2 = unpk_fp8(t2), v3 = unpk_fp8(t3);
        ax0 += v0[0]; ay0 += v0[1]; ax1 += v1[0]; ay1 += v1[1];
        ax2 += v2[0]; ay2 += v2[1]; ax3 += v3[0]; ay3 += v3[1];
        e += 4;
    }
    for (; e < n; ++e) {
        unsigned short t = *(const unsigned short*)(ybl + (size_t)bk[e] * 128);
        f32x2 v = unpk_fp8(t);
        ax0 += v[0]; ay0 += v[1];
    }
    float inv = 1.0f / fmaxf((float)deg, 1.0f);
    float mx = ((ax0 + ax1) + (ax2 + ax3)) * inv;
    float my = ((ay0 + ay1) + (ay2 + ay3)) * inv;

    float h0 = fmaxf(bflo(zu) + mx, 0.f);       // col colA
    float h1v = fmaxf(bfhi(zu) + my, 0.f);      // col colB

    float p0 = h0 * wsA.x + h1v * wsB.x;
    float p1 = h0 * wsA.y + h1v * wsB.y;
    float q0 = h0 * wnA.x + h1v * wnB.x;
    float q1 = h0 * wnA.y + h1v * wnB.y;
#pragma unroll
    for (int off = 32; off >= 1; off >>= 1) {
        p0 += __shfl_xor(p0, off, 64);
        p1 += __shfl_xor(p1, off, 64);
        q0 += __shfl_xor(q0, off, 64);
        q1 += __shfl_xor(q1, off, 64);
    }
    if (lane == 0) {
        float4 o; o.x = p0; o.y = p1; o.z = q0; o.w = q1;
        ((float4*)pq)[node] = o;
    }
}

// ---------------- K3: out[n] = pq[n].p + mean_src(pq[src].q) + bc ----------------
__global__ __launch_bounds__(256) void k_final(const float* __restrict__ pq,
                                               const int* __restrict__ cnt,
                                               const unsigned short* __restrict__ bucket,
                                               const float* __restrict__ wc,
                                               float* __restrict__ out) {
    int blk = blockIdx.x;
    int wavein = threadIdx.x >> 6;
    int lane = threadIdx.x & 63;
    int xcd = blk & 7;
    int i = (blk >> 3) * 4 + wavein;
    int b = xcd + ((i >> 9) << 3);
    if (b >= NBIN) return;
    int node = (b << 9) + (i & 511);
    if (node >= N_NODES) return;

    int deg = cnt[node];
    int n = deg < CAP ? deg : CAP;
    float qx = 0.f, qy = 0.f;
    if (lane < n) {
        int s = bucket[(size_t)node * CAP + lane];
        float2 q = *(const float2*)(pq + (size_t)s * 4 + 2);
        qx = q.x; qy = q.y;
    }
#pragma unroll
    for (int off = 32; off >= 1; off >>= 1) {
        qx += __shfl_xor(qx, off, 64);
        qy += __shfl_xor(qy, off, 64);
    }
    if (lane == 0) {
        float inv = 1.0f / fmaxf((float)deg, 1.0f);
        float2 p = *(const float2*)(pq + (size_t)node * 4);
        out[(size_t)node * 2 + 0] = p.x + qx * inv + wc[512];
        out[(size_t)node * 2 + 1] = p.y + qy * inv + wc[513];
    }
}

extern "C" void kernel_launch(void* const* d_in, const int* in_sizes, int n_in,
                              void* d_out, int out_size, void* d_ws, size_t ws_size,
                              hipStream_t stream) {
    const float* x   = (const float*)d_in[0];
    const int* esrc  = (const int*)d_in[1];
    const int* edst  = (const int*)d_in[2];
    const float* W1s = (const float*)d_in[3];
    const float* W1n = (const float*)d_in[4];
    const float* b1  = (const float*)d_in[5];
    const float* W2s = (const float*)d_in[6];
    const float* W2n = (const float*)d_in[7];
    const float* b2  = (const float*)d_in[8];
    const float* Wf  = (const float*)d_in[9];
    const float* bf  = (const float*)d_in[10];
    float* out = (float*)d_out;

    char* ws = (char*)d_ws;
    auto alloc = [&](size_t bytes) {
        char* p = ws;
        ws += (bytes + 255) & ~(size_t)255;
        return p;
    };
    int*            cnt    = (int*)           alloc((size_t)N_NODES * 4);
    unsigned short* bucket = (unsigned short*)alloc((size_t)N_NODES * CAP * 2);
    unsigned*       seg    = (unsigned*)      alloc((size_t)NBIN * N_PARTS * NSLOT * 4);
    int*            segcnt = (int*)           alloc((size_t)NBIN * N_PARTS * 4);
    unsigned short* zb     = (unsigned short*)alloc((size_t)N_NODES * 128 * 2);
    unsigned char*  yb8    = (unsigned char*) alloc((size_t)N_NODES * 128);
    unsigned short* wpack  = (unsigned short*)alloc(8 * 8 * 64 * 8 * 2);
    float*          pq     = (float*)         alloc((size_t)N_NODES * 4 * 4);
    float*          wc     = (float*)         alloc(1024 * 4);

    k_pre<<<NB_PRE, 256, 0, stream>>>(esrc, edst, W1s, W1n, W2s, W2n, b2, Wf, bf,
                                      seg, segcnt, wpack, wc);
    k_main<<<NB_MAIN, 512, 0, stream>>>(x, seg, segcnt, wpack, b1, cnt, bucket, zb, yb8);
    k_agg2<<<NB_AGG, 256, 0, stream>>>(yb8, zb, cnt, bucket, wc, pq);
    k_final<<<NB_AGG, 256, 0, stream>>>(pq, cnt, bucket, wc, out);
}